// Round 9
// baseline (136.877 us; speedup 1.0000x reference)
//
#include <hip/hip_runtime.h>
#include <hip/hip_bf16.h>
#include <cstdint>

#define NHEADS 8
#define NPOINTS 4

typedef __bf16 bf16x8 __attribute__((ext_vector_type(8)));
typedef float f32x4 __attribute__((ext_vector_type(4)));

__device__ __forceinline__ ushort f2bf_rn(float x) {
  union { float f; uint32_t u; } c; c.f = x;
  uint32_t r = c.u + 0x7fffu + ((c.u >> 16) & 1u);
  return (ushort)(r >> 16);
}
__device__ __forceinline__ float bf2f(ushort h) {
  union { uint32_t u; float f; } c; c.u = ((uint32_t)h) << 16; return c.f;
}
__device__ __forceinline__ uint pack2(ushort a, ushort b) {
  return (uint)a | ((uint)b << 16);
}

// ---------------------------------------------------------------------------
// Split-bf16 (3x MFMA) GEMM, N=256, K=256: C = A @ B + bias.
// ROUND-9 STRUCTURE: BARRIER-FREE, LDS-FREE K-loop.
//  - Each wave loads its OWN A fragments straight from global in MFMA
//    fragment layout (lane(lrow,lgrp) reads A[mt*16+lrow][t*32+lgrp*8..+8],
//    32B contiguous). The 4 waves redundantly read the same 8 KB/step ->
//    L1/L2 absorbs; HBM still reads A once.
//  - hi/lo split done IN REGISTERS (fragment layout == register layout).
//  - B fragment-ready from Bprep (1 KB/wave coalesced dwordx4 loads).
//  - NO __syncthreads, NO LDS in the loop -> no lockstep, no vmcnt(0)
//    drain; K fully unrolled so the compiler pipelines across steps.
// LDS used only by the store epilogue (full-line coalesced C writes).
// ---------------------------------------------------------------------------
template<int TM>
__global__ __launch_bounds__(256, 3) void gemm_split3_n256(
    const float* __restrict__ A,
    const ushort* __restrict__ Bprep,   // [8][4 waves][8 frag][512] ushorts
    const float* __restrict__ bias, float* __restrict__ C,
    int M)
{
  constexpr int MT = TM / 16;
  constexpr int K = 256;
  __shared__ float ctile[16 * 260];
  const int tid  = threadIdx.x;
  const int lane = tid & 63, wave = tid >> 6;
  const int wn   = wave * 64;
  const int lrow = lane & 15, lgrp = lane >> 4;
  const long brow = (long)blockIdx.x * TM;

  f32x4 acc[MT][4] = {};

  // Per-lane A fragment row pointers (k-offset lgrp*8 folded in).
  const float* Arow[MT];
#pragma unroll
  for (int mt = 0; mt < MT; ++mt)
    Arow[mt] = &A[(size_t)(brow + mt * 16 + lrow) * K + lgrp * 8];

  const ushort* Bw = Bprep + wave * 4096 + lane * 8;

#pragma unroll
  for (int t = 0; t < 8; ++t) {
    // ---- B fragments: coalesced dwordx4 from L2-resident Bprep ----
    uint4 braw[8];
#pragma unroll
    for (int f = 0; f < 8; ++f)
      braw[f] = *(const uint4*)(Bw + (size_t)t * 16384 + f * 512);

    // ---- A fragments: direct global loads (32 B/lane per mt) ----
    float4 a0[MT], a1[MT];
#pragma unroll
    for (int mt = 0; mt < MT; ++mt) {
      a0[mt] = *(const float4*)(Arow[mt] + t * 32);
      a1[mt] = *(const float4*)(Arow[mt] + t * 32 + 4);
    }

    // ---- per-mt: in-register hi/lo split, then 12 MFMAs ----
#pragma unroll
    for (int mt = 0; mt < MT; ++mt) {
      const float v[8] = {a0[mt].x, a0[mt].y, a0[mt].z, a0[mt].w,
                          a1[mt].x, a1[mt].y, a1[mt].z, a1[mt].w};
      ushort h[8], l[8];
#pragma unroll
      for (int j = 0; j < 8; ++j) {
        h[j] = f2bf_rn(v[j]);
        l[j] = f2bf_rn(v[j] - bf2f(h[j]));
      }
      uint4 hu = {pack2(h[0],h[1]), pack2(h[2],h[3]), pack2(h[4],h[5]), pack2(h[6],h[7])};
      uint4 lu = {pack2(l[0],l[1]), pack2(l[2],l[3]), pack2(l[4],l[5]), pack2(l[6],l[7])};
      const bf16x8 ah = *(const bf16x8*)&hu;
      const bf16x8 al = *(const bf16x8*)&lu;
#pragma unroll
      for (int nt = 0; nt < 4; ++nt) {
        const bf16x8 bh = *(const bf16x8*)&braw[nt * 2];
        const bf16x8 bl = *(const bf16x8*)&braw[nt * 2 + 1];
        acc[mt][nt] = __builtin_amdgcn_mfma_f32_16x16x32_bf16(ah, bh, acc[mt][nt], 0, 0, 0);
        acc[mt][nt] = __builtin_amdgcn_mfma_f32_16x16x32_bf16(ah, bl, acc[mt][nt], 0, 0, 0);
        acc[mt][nt] = __builtin_amdgcn_mfma_f32_16x16x32_bf16(al, bh, acc[mt][nt], 0, 0, 0);
      }
    }
  }

  // ---- epilogue: 16-row passes through LDS, full-line coalesced stores ----
  float bb[4];
#pragma unroll
  for (int nt = 0; nt < 4; ++nt) bb[nt] = bias[wn + nt * 16 + lrow];
#pragma unroll
  for (int h = 0; h < MT; ++h) {
    __syncthreads();
#pragma unroll
    for (int nt = 0; nt < 4; ++nt) {
      const int col = wn + nt * 16 + lrow;
#pragma unroll
      for (int j = 0; j < 4; ++j)
        ctile[(lgrp * 4 + j) * 260 + col] = acc[h][nt][j] + bb[nt];
    }
    __syncthreads();
#pragma unroll
    for (int i = 0; i < 4; ++i) {   // 16 rows * 64 float4 / 256 threads
      const int idx = i * 256 + tid, r = idx >> 6, c4 = (idx & 63) << 2;
      *(float4*)&C[(size_t)(brow + h * 16 + r) * 256 + c4] = *(const float4*)&ctile[r * 260 + c4];
    }
  }
}

// ---------------------------------------------------------------------------
// Weight prep: W fp32 [256][256] -> Bprep fragment-ready layout.
// Bprep ushort index = ((t*4 + w)*8 + nt*2 + h)*512 + lane*8 + j  where
// value = plane_h( W[k][col] ), k = t*32 + (lane>>4)*8 + j,
// col = w*64 + nt*16 + (lane&15).
// ---------------------------------------------------------------------------
__global__ __launch_bounds__(256) void prep_wt(
    const float* __restrict__ W, ushort* __restrict__ Bprep)
{
  const int gid = blockIdx.x * 256 + threadIdx.x;  // 0..131071
  const int j    = gid & 7;
  const int lane = (gid >> 3) & 63;
  const int sub  = gid >> 9;          // t*32 + w*8 + nt*2 + h
  const int h  = sub & 1;
  const int nt = (sub >> 1) & 3;
  const int w  = (sub >> 3) & 3;
  const int t  = sub >> 5;
  const int k   = t * 32 + (lane >> 4) * 8 + j;
  const int col = w * 64 + nt * 16 + (lane & 15);
  const float v = W[(size_t)k * 256 + col];
  const ushort hi = f2bf_rn(v);
  Bprep[gid] = h ? f2bf_rn(v - bf2f(hi)) : hi;
}

// ---------------------------------------------------------------------------
// Offsets + attention-logits projection (unchanged).
// ---------------------------------------------------------------------------
__global__ __launch_bounds__(128) void proj_kernel(
    const float* __restrict__ query,
    const float* __restrict__ W_off, const float* __restrict__ b_off,
    const float* __restrict__ W_attn, const float* __restrict__ b_attn,
    float* __restrict__ offs, float* __restrict__ logits)
{
  __shared__ float q_lds[8][256];
  const int row0 = blockIdx.x * 8;
  const int tid  = threadIdx.x;

  for (int i = tid; i < 512; i += 128) {
    const int r  = i >> 6;
    const int c4 = (i & 63) << 2;
    *(float4*)&q_lds[r][c4] = *(const float4*)&query[(size_t)(row0 + r) * 256 + c4];
  }
  __syncthreads();
  if (tid >= 96) return;

  float acc[8] = {};
  if (tid < 64) {
    for (int k4 = 0; k4 < 256; k4 += 4) {
      const float w0 = W_off[(k4 + 0) * 64 + tid];
      const float w1 = W_off[(k4 + 1) * 64 + tid];
      const float w2 = W_off[(k4 + 2) * 64 + tid];
      const float w3 = W_off[(k4 + 3) * 64 + tid];
#pragma unroll
      for (int r = 0; r < 8; ++r) {
        float4 q4 = *(const float4*)&q_lds[r][k4];
        acc[r] += q4.x * w0 + q4.y * w1 + q4.z * w2 + q4.w * w3;
      }
    }
    const float bb = b_off[tid];
#pragma unroll
    for (int r = 0; r < 8; ++r)
      offs[(size_t)(row0 + r) * 64 + tid] = acc[r] + bb;
  } else {
    const int j = tid - 64;
    for (int k4 = 0; k4 < 256; k4 += 4) {
      const float w0 = W_attn[(k4 + 0) * 32 + j];
      const float w1 = W_attn[(k4 + 1) * 32 + j];
      const float w2 = W_attn[(k4 + 2) * 32 + j];
      const float w3 = W_attn[(k4 + 3) * 32 + j];
#pragma unroll
      for (int r = 0; r < 8; ++r) {
        float4 q4 = *(const float4*)&q_lds[r][k4];
        acc[r] += q4.x * w0 + q4.y * w1 + q4.z * w2 + q4.w * w3;
      }
    }
    const float bb = b_attn[j];
#pragma unroll
    for (int r = 0; r < 8; ++r)
      logits[(size_t)(row0 + r) * 32 + j] = acc[r] + bb;
  }
}

// ---------------------------------------------------------------------------
// Softmax + bilinear sampling, wave-per-query, float4 per lane (unchanged).
// ---------------------------------------------------------------------------
__global__ __launch_bounds__(256, 8) void sample_kernel(
    const float* __restrict__ refp,    // [BQ,2]
    const float* __restrict__ offs,    // [BQ,64]  (h*8 + p*2 + c)
    const float* __restrict__ logits,  // [BQ,32]  (h*4 + p)
    const float* __restrict__ values,  // [B,HW,256]
    float* __restrict__ mid,           // [BQ,256]
    const int* __restrict__ hptr, const int* __restrict__ wptr,
    int Q, int HW)
{
  const int lane = threadIdx.x & 63;
  const int bq   = blockIdx.x * 4 + (threadIdx.x >> 6);
  const int b    = bq / Q;
  const int W_   = *wptr;
  const int H_   = *hptr;
  const int h    = lane >> 3;

  const float l0 = logits[(size_t)bq * 32 + h * 4 + 0];
  const float l1 = logits[(size_t)bq * 32 + h * 4 + 1];
  const float l2 = logits[(size_t)bq * 32 + h * 4 + 2];
  const float l3 = logits[(size_t)bq * 32 + h * 4 + 3];
  const float m  = fmaxf(fmaxf(l0, l1), fmaxf(l2, l3));
  const float e0 = __expf(l0 - m), e1 = __expf(l1 - m);
  const float e2 = __expf(l2 - m), e3 = __expf(l3 - m);
  const float inv = 1.0f / (e0 + e1 + e2 + e3);
  float wt[4] = {e0 * inv, e1 * inv, e2 * inv, e3 * inv};

  const float rx = refp[(size_t)bq * 2 + 0];
  const float ry = refp[(size_t)bq * 2 + 1];
  const float* vb = values + (size_t)b * HW * 256;
  const int ch = lane * 4;

  f32x4 acc = {0.f, 0.f, 0.f, 0.f};
#pragma unroll
  for (int p = 0; p < NPOINTS; ++p) {
    float lx = rx + offs[(size_t)bq * 64 + h * 8 + p * 2 + 0];
    float ly = ry + offs[(size_t)bq * 64 + h * 8 + p * 2 + 1];
    lx = fminf(fmaxf(lx, 0.0f), 1.0f);
    ly = fminf(fmaxf(ly, 0.0f), 1.0f);
    const float sx = lx * (float)(W_ - 1);
    const float sy = ly * (float)(H_ - 1);
    int x0 = (int)floorf(sx);
    int y0 = (int)floorf(sy);
    x0 = min(max(x0, 0), W_ - 1);
    y0 = min(max(y0, 0), H_ - 1);
    const int x1 = min(x0 + 1, W_ - 1);
    const int y1 = min(y0 + 1, H_ - 1);
    const float wx1 = sx - (float)x0, wx0 = 1.0f - wx1;
    const float wy1 = sy - (float)y0, wy0 = 1.0f - wy1;

    const f32x4 g00 = *(const f32x4*)&vb[(size_t)(y0 * W_ + x0) * 256 + ch];
    const f32x4 g10 = *(const f32x4*)&vb[(size_t)(y0 * W_ + x1) * 256 + ch];
    const f32x4 g01 = *(const f32x4*)&vb[(size_t)(y1 * W_ + x0) * 256 + ch];
    const f32x4 g11 = *(const f32x4*)&vb[(size_t)(y1 * W_ + x1) * 256 + ch];

    const float w00 = wx0 * wy0, w10 = wx1 * wy0, w01 = wx0 * wy1, w11 = wx1 * wy1;
    const float wp = wt[p];
#pragma unroll
    for (int j = 0; j < 4; ++j)
      acc[j] += wp * (g00[j] * w00 + g01[j] * w01 + g10[j] * w10 + g11[j] * w11);
  }
  *(f32x4*)&mid[(size_t)bq * 256 + ch] = acc;
}

// ---------------------------------------------------------------------------
extern "C" void kernel_launch(void* const* d_in, const int* in_sizes, int n_in,
                              void* d_out, int out_size, void* d_ws, size_t ws_size,
                              hipStream_t stream)
{
  const float* query   = (const float*)d_in[0];
  const float* refp    = (const float*)d_in[1];
  const float* input_f = (const float*)d_in[2];
  const int*   hptr    = (const int*)d_in[3];
  const int*   wptr    = (const int*)d_in[4];
  const float* W_off   = (const float*)d_in[5];
  const float* b_off   = (const float*)d_in[6];
  const float* W_attn  = (const float*)d_in[7];
  const float* b_attn  = (const float*)d_in[8];
  const float* W_val   = (const float*)d_in[9];
  const float* b_val   = (const float*)d_in[10];
  const float* W_out   = (const float*)d_in[11];
  const float* b_out   = (const float*)d_in[12];
  float* out = (float*)d_out;

  const int D   = 256;
  const int BQ  = in_sizes[0] / D;   // 16384
  const int B   = 8;
  const int Q   = BQ / B;            // 2048
  const int BHW = in_sizes[2] / D;   // 80000
  const int HW  = BHW / B;           // 10000

  char* ws = (char*)d_ws;
  float* values = (float*)ws;                                   // 81.92 MB
  size_t o = (size_t)BHW * D * sizeof(float);
  float* offsb  = (float*)(ws + o);  o += (size_t)BQ * 64 * sizeof(float);  // 4.19 MB
  float* logitb = (float*)(ws + o);  o += (size_t)BQ * 32 * sizeof(float);  // 2.10 MB
  float* mid    = (float*)(ws + o);                             // 16.78 MB

  // Fragment-ready weight overlays on dead regions (256 KB each):
  //  - Bprep_val at head of `mid` (dead until sample writes mid)
  //  - Bprep_out at head of `offsb` (offs dead after sample; prep#2 runs after)
  ushort* Bprep_val = (ushort*)mid;
  ushort* Bprep_out = (ushort*)offsb;

  // 1. values = input_flatten @ W_val + b_val
  prep_wt<<<512, 256, 0, stream>>>(W_val, Bprep_val);
  gemm_split3_n256<64><<<BHW / 64, 256, 0, stream>>>(
      input_f, Bprep_val, b_val, values, BHW);

  // 2. offsets + attention logits
  proj_kernel<<<BQ / 8, 128, 0, stream>>>(
      query, W_off, b_off, W_attn, b_attn, offsb, logitb);

  // 3. softmax + bilinear sampling -> mid
  sample_kernel<<<BQ / 4, 256, 0, stream>>>(
      refp, offsb, logitb, values, mid, hptr, wptr, Q, HW);

  // 4. out = mid @ W_out + b_out
  prep_wt<<<512, 256, 0, stream>>>(W_out, Bprep_out);
  gemm_split3_n256<32><<<BQ / 32, 256, 0, stream>>>(
      mid, Bprep_out, b_out, out, BQ);
}

// Round 10
// 122.406 us; speedup vs baseline: 1.1182x; 1.1182x over previous
//
#include <hip/hip_runtime.h>
#include <hip/hip_bf16.h>
#include <cstdint>

#define NHEADS 8
#define NPOINTS 4

typedef __bf16 bf16x8 __attribute__((ext_vector_type(8)));
typedef float f32x4 __attribute__((ext_vector_type(4)));

#define AS1 __attribute__((address_space(1)))
#define AS3 __attribute__((address_space(3)))

__device__ __forceinline__ ushort f2bf_rn(float x) {
  union { float f; uint32_t u; } c; c.f = x;
  uint32_t r = c.u + 0x7fffu + ((c.u >> 16) & 1u);
  return (ushort)(r >> 16);
}
__device__ __forceinline__ float bf2f(ushort h) {
  union { uint32_t u; float f; } c; c.u = ((uint32_t)h) << 16; return c.f;
}
__device__ __forceinline__ uint pack2(ushort a, ushort b) {
  return (uint)a | ((uint)b << 16);
}

// LDS rows are 128 B = 8 granules of 16 B: granules 0-3 = hi (32 bf16 of k),
// granules 4-7 = lo. Granule index XOR-swizzled by (row&7) (conflict-free,
// verified rounds 3-9). Returns ushort index.
__device__ __forceinline__ int gidx(int row, int g0) {
  return row * 64 + ((g0 ^ (row & 7)) << 3);
}

// Convert one thread's A chunk (fp32 -> hi/lo bf16) and store to LDS buffer.
template<int TM>
__device__ __forceinline__ void a_convert_store(
    ushort* Ab, int arow, int agq, float4 areg0, float4 areg1)
{
  if constexpr (TM == 64) {
    const float v[8] = {areg0.x, areg0.y, areg0.z, areg0.w,
                        areg1.x, areg1.y, areg1.z, areg1.w};
    ushort h[8], l[8];
#pragma unroll
    for (int j = 0; j < 8; ++j) {
      h[j] = f2bf_rn(v[j]);
      l[j] = f2bf_rn(v[j] - bf2f(h[j]));
    }
    uint4 hv = {pack2(h[0],h[1]), pack2(h[2],h[3]), pack2(h[4],h[5]), pack2(h[6],h[7])};
    uint4 lv = {pack2(l[0],l[1]), pack2(l[2],l[3]), pack2(l[4],l[5]), pack2(l[6],l[7])};
    *(uint4*)&Ab[gidx(arow, agq)]     = hv;
    *(uint4*)&Ab[gidx(arow, agq + 4)] = lv;
  } else {
    const float v[4] = {areg0.x, areg0.y, areg0.z, areg0.w};
    ushort h[4], l[4];
#pragma unroll
    for (int j = 0; j < 4; ++j) {
      h[j] = f2bf_rn(v[j]);
      l[j] = f2bf_rn(v[j] - bf2f(h[j]));
    }
    const int g = agq >> 1, half = (agq & 1) * 4;
    uint2 hv = {pack2(h[0],h[1]), pack2(h[2],h[3])};
    uint2 lv = {pack2(l[0],l[1]), pack2(l[2],l[3])};
    *(uint2*)&Ab[gidx(arow, g)     + half] = hv;
    *(uint2*)&Ab[gidx(arow, g + 4) + half] = lv;
  }
}

// ---------------------------------------------------------------------------
// Split-bf16 (3x MFMA) GEMM, N=256, K=256: C = A @ B + bias.
// ROUND-10: r5 pipeline + T4 counted-vmcnt barriers.
//  - B LDS quarters are WAVE-PRIVATE (glds dest wave*4096+j*512 == the range
//    this wave's ds_reads cover) -> B needs NO barrier, only vmcnt.
//  - K-loop barrier is raw s_barrier + lgkmcnt(0) ONLY (A ds_writes); the
//    10 in-flight prefetch loads (2 A + 8 B) CROSS the barrier (unlike
//    __syncthreads, which forces vmcnt(0) - the r5-r8 stall).
//  - asm vmcnt(10/9) before the MFMA phase = wait only for B(t), keeping
//    B(t+1)/A(t+1) in flight under the 48 MFMAs.
//  - Loop fully unrolled (NT=8): buffer selects are compile-time.
// LDS: 2*(TM*128B) A + 2*32KB B = 80KB @ TM=64 (2 blocks/CU).
// ---------------------------------------------------------------------------
template<int TM>
__global__ __launch_bounds__(256, 2) void gemm_split3_n256(
    const float* __restrict__ A,
    const ushort* __restrict__ Bprep,   // [8][16384] pre-swizzled ushorts
    const float* __restrict__ bias, float* __restrict__ C,
    int M)
{
  constexpr int MT = TM / 16;
  constexpr int AH = TM * 64;          // ushorts per A buffer
  constexpr int BH = 16384;            // ushorts per B buffer
  __shared__ ushort smem[2 * AH + 2 * BH];
  const int tid  = threadIdx.x;
  const int lane = tid & 63, wave = tid >> 6;
  const int wn   = wave * 64;
  const int lrow = lane & 15, lgrp = lane >> 4;
  const long brow = (long)blockIdx.x * TM;

  f32x4 acc[MT][4] = {};

  int arow, agq;
  if constexpr (TM == 64) { arow = tid >> 2; agq = tid & 3; }
  else                    { arow = tid >> 3; agq = tid & 7; }
  const float* Abase = &A[(size_t)(brow + arow) * 256];

  float4 areg0 = {}, areg1 = {};

  // ---- prologue: A(0)->regs first (oldest), then B(0) glds, convert, bar ----
  if constexpr (TM == 64) {
    areg0 = *(const float4*)(Abase + agq * 8);
    areg1 = *(const float4*)(Abase + agq * 8 + 4);
  } else {
    areg0 = *(const float4*)(Abase + agq * 4);
  }
  __builtin_amdgcn_sched_barrier(0);
#pragma unroll
  for (int j = 0; j < 8; ++j)
    __builtin_amdgcn_global_load_lds(
        (const AS1 void*)(Bprep + wave * 4096 + j * 512 + lane * 8),
        (AS3 void*)(smem + 2 * AH + wave * 4096 + j * 512), 16, 0, 0);
  a_convert_store<TM>(smem, arow, agq, areg0, areg1);
  asm volatile("s_waitcnt lgkmcnt(0)" ::: "memory");
  __builtin_amdgcn_s_barrier();
  __builtin_amdgcn_sched_barrier(0);

#pragma unroll
  for (int t = 0; t < 8; ++t) {
    constexpr int unused = 0; (void)unused;
    const int p  = t & 1;                 // compile-time after unroll
    const int tn = (t + 1) & 7;           // wrap keeps vmcnt math uniform
    ushort* Acur = smem + p * AH;
    ushort* Anxt = smem + (p ^ 1) * AH;
    ushort* Bcur = smem + 2 * AH + p * BH;
    ushort* Bnxt = smem + 2 * AH + (p ^ 1) * BH;

    // ---- issue A(tn) reg loads FIRST (must be oldest of this step) ----
    if constexpr (TM == 64) {
      areg0 = *(const float4*)(Abase + tn * 32 + agq * 8);
      areg1 = *(const float4*)(Abase + tn * 32 + agq * 8 + 4);
    } else {
      areg0 = *(const float4*)(Abase + tn * 32 + agq * 4);
    }
    __builtin_amdgcn_sched_barrier(0);

    // ---- issue B(tn) glds into wave-private quarter of the other buffer ----
#pragma unroll
    for (int j = 0; j < 8; ++j)
      __builtin_amdgcn_global_load_lds(
          (const AS1 void*)(Bprep + (size_t)tn * BH + wave * 4096 + j * 512 + lane * 8),
          (AS3 void*)(Bnxt + wave * 4096 + j * 512), 16, 0, 0);

    // ---- wait ONLY for B(t): keep the 10 (9) newest loads in flight ----
    if constexpr (TM == 64)
      asm volatile("s_waitcnt vmcnt(10)" ::: "memory");
    else
      asm volatile("s_waitcnt vmcnt(9)" ::: "memory");
    __builtin_amdgcn_sched_barrier(0);

    // ---- MFMA(t) ----
    bf16x8 ah[MT], al[MT];
#pragma unroll
    for (int mt = 0; mt < MT; ++mt) {
      const int r = mt * 16 + lrow;
      ah[mt] = *(const bf16x8*)&Acur[gidx(r, lgrp)];
      al[mt] = *(const bf16x8*)&Acur[gidx(r, lgrp + 4)];
    }
#pragma unroll
    for (int nt = 0; nt < 4; ++nt) {
      const int r = wn + nt * 16 + lrow;
      const bf16x8 bh = *(const bf16x8*)&Bcur[gidx(r, lgrp)];
      const bf16x8 bl = *(const bf16x8*)&Bcur[gidx(r, lgrp + 4)];
#pragma unroll
      for (int mt = 0; mt < MT; ++mt) {
        acc[mt][nt] = __builtin_amdgcn_mfma_f32_16x16x32_bf16(ah[mt], bh, acc[mt][nt], 0, 0, 0);
        acc[mt][nt] = __builtin_amdgcn_mfma_f32_16x16x32_bf16(ah[mt], bl, acc[mt][nt], 0, 0, 0);
        acc[mt][nt] = __builtin_amdgcn_mfma_f32_16x16x32_bf16(al[mt], bh, acc[mt][nt], 0, 0, 0);
      }
    }

    // ---- convert + ds_write A(tn) (compiler waits vmcnt(8) for aregs) ----
    a_convert_store<TM>(Anxt, arow, agq, areg0, areg1);

    // ---- raw barrier: lgkm only — VMEM prefetches stay in flight ----
    asm volatile("s_waitcnt lgkmcnt(0)" ::: "memory");
    __builtin_amdgcn_s_barrier();
    __builtin_amdgcn_sched_barrier(0);
  }

  // ---- epilogue: full drain, then LDS-staged full-line C stores ----
  asm volatile("s_waitcnt vmcnt(0) lgkmcnt(0)" ::: "memory");
  __syncthreads();
  float bb[4];
#pragma unroll
  for (int nt = 0; nt < 4; ++nt) bb[nt] = bias[wn + nt * 16 + lrow];
  float* ctile = (float*)smem;               // 16 x 260 floats = 16.6 KB
#pragma unroll
  for (int h = 0; h < MT; ++h) {
    __syncthreads();
#pragma unroll
    for (int nt = 0; nt < 4; ++nt) {
      const int col = wn + nt * 16 + lrow;
#pragma unroll
      for (int j = 0; j < 4; ++j)
        ctile[(lgrp * 4 + j) * 260 + col] = acc[h][nt][j] + bb[nt];
    }
    __syncthreads();
#pragma unroll
    for (int i = 0; i < 4; ++i) {   // 16 rows * 64 float4 / 256 threads
      const int idx = i * 256 + tid, r = idx >> 6, c4 = (idx & 63) << 2;
      *(float4*)&C[(size_t)(brow + h * 16 + r) * 256 + c4] = *(const float4*)&ctile[r * 260 + c4];
    }
  }
}

// ---------------------------------------------------------------------------
// Weight prep: W fp32 [256][256] -> Bprep (pre-swizzled, K-step-tiled).
// Chunk t (16384 ushorts) is the exact LDS image for K-step t: row r holds
// [hi granules 0-3 | lo granules 4-7] of W[32t..32t+32][r], granule-XOR-
// swizzled by (r&7). glds copy it linearly; reads un-swizzle. (Unchanged.)
// ---------------------------------------------------------------------------
__global__ __launch_bounds__(256) void prep_wt(
    const float* __restrict__ W, ushort* __restrict__ Bprep)
{
  const int pg = blockIdx.x * 256 + threadIdx.x;  // 0..131071
  const int t = pg >> 14;
  const int p = pg & 16383;
  const int r = p >> 6;
  const int q = p & 63;
  const int g0 = (q >> 3) ^ (r & 7);              // unswizzled granule
  const int q0 = g0 * 8 + (q & 7);                // unswizzled ushort in row
  const int kk = q0 & 31;
  const float w = W[(size_t)(t * 32 + kk) * 256 + r];
  const ushort hi = f2bf_rn(w);
  Bprep[pg] = (q0 < 32) ? hi : f2bf_rn(w - bf2f(hi));
}

// ---------------------------------------------------------------------------
// Offsets + attention-logits projection (unchanged).
// ---------------------------------------------------------------------------
__global__ __launch_bounds__(128) void proj_kernel(
    const float* __restrict__ query,
    const float* __restrict__ W_off, const float* __restrict__ b_off,
    const float* __restrict__ W_attn, const float* __restrict__ b_attn,
    float* __restrict__ offs, float* __restrict__ logits)
{
  __shared__ float q_lds[8][256];
  const int row0 = blockIdx.x * 8;
  const int tid  = threadIdx.x;

  for (int i = tid; i < 512; i += 128) {
    const int r  = i >> 6;
    const int c4 = (i & 63) << 2;
    *(float4*)&q_lds[r][c4] = *(const float4*)&query[(size_t)(row0 + r) * 256 + c4];
  }
  __syncthreads();
  if (tid >= 96) return;

  float acc[8] = {};
  if (tid < 64) {
    for (int k4 = 0; k4 < 256; k4 += 4) {
      const float w0 = W_off[(k4 + 0) * 64 + tid];
      const float w1 = W_off[(k4 + 1) * 64 + tid];
      const float w2 = W_off[(k4 + 2) * 64 + tid];
      const float w3 = W_off[(k4 + 3) * 64 + tid];
#pragma unroll
      for (int r = 0; r < 8; ++r) {
        float4 q4 = *(const float4*)&q_lds[r][k4];
        acc[r] += q4.x * w0 + q4.y * w1 + q4.z * w2 + q4.w * w3;
      }
    }
    const float bb = b_off[tid];
#pragma unroll
    for (int r = 0; r < 8; ++r)
      offs[(size_t)(row0 + r) * 64 + tid] = acc[r] + bb;
  } else {
    const int j = tid - 64;
    for (int k4 = 0; k4 < 256; k4 += 4) {
      const float w0 = W_attn[(k4 + 0) * 32 + j];
      const float w1 = W_attn[(k4 + 1) * 32 + j];
      const float w2 = W_attn[(k4 + 2) * 32 + j];
      const float w3 = W_attn[(k4 + 3) * 32 + j];
#pragma unroll
      for (int r = 0; r < 8; ++r) {
        float4 q4 = *(const float4*)&q_lds[r][k4];
        acc[r] += q4.x * w0 + q4.y * w1 + q4.z * w2 + q4.w * w3;
      }
    }
    const float bb = b_attn[j];
#pragma unroll
    for (int r = 0; r < 8; ++r)
      logits[(size_t)(row0 + r) * 32 + j] = acc[r] + bb;
  }
}

// ---------------------------------------------------------------------------
// Softmax + bilinear sampling, wave-per-query, float4 per lane (unchanged).
// ---------------------------------------------------------------------------
__global__ __launch_bounds__(256, 8) void sample_kernel(
    const float* __restrict__ refp,    // [BQ,2]
    const float* __restrict__ offs,    // [BQ,64]  (h*8 + p*2 + c)
    const float* __restrict__ logits,  // [BQ,32]  (h*4 + p)
    const float* __restrict__ values,  // [B,HW,256]
    float* __restrict__ mid,           // [BQ,256]
    const int* __restrict__ hptr, const int* __restrict__ wptr,
    int Q, int HW)
{
  const int lane = threadIdx.x & 63;
  const int bq   = blockIdx.x * 4 + (threadIdx.x >> 6);
  const int b    = bq / Q;
  const int W_   = *wptr;
  const int H_   = *hptr;
  const int h    = lane >> 3;

  const float l0 = logits[(size_t)bq * 32 + h * 4 + 0];
  const float l1 = logits[(size_t)bq * 32 + h * 4 + 1];
  const float l2 = logits[(size_t)bq * 32 + h * 4 + 2];
  const float l3 = logits[(size_t)bq * 32 + h * 4 + 3];
  const float m  = fmaxf(fmaxf(l0, l1), fmaxf(l2, l3));
  const float e0 = __expf(l0 - m), e1 = __expf(l1 - m);
  const float e2 = __expf(l2 - m), e3 = __expf(l3 - m);
  const float inv = 1.0f / (e0 + e1 + e2 + e3);
  float wt[4] = {e0 * inv, e1 * inv, e2 * inv, e3 * inv};

  const float rx = refp[(size_t)bq * 2 + 0];
  const float ry = refp[(size_t)bq * 2 + 1];
  const float* vb = values + (size_t)b * HW * 256;
  const int ch = lane * 4;

  f32x4 acc = {0.f, 0.f, 0.f, 0.f};
#pragma unroll
  for (int p = 0; p < NPOINTS; ++p) {
    float lx = rx + offs[(size_t)bq * 64 + h * 8 + p * 2 + 0];
    float ly = ry + offs[(size_t)bq * 64 + h * 8 + p * 2 + 1];
    lx = fminf(fmaxf(lx, 0.0f), 1.0f);
    ly = fminf(fmaxf(ly, 0.0f), 1.0f);
    const float sx = lx * (float)(W_ - 1);
    const float sy = ly * (float)(H_ - 1);
    int x0 = (int)floorf(sx);
    int y0 = (int)floorf(sy);
    x0 = min(max(x0, 0), W_ - 1);
    y0 = min(max(y0, 0), H_ - 1);
    const int x1 = min(x0 + 1, W_ - 1);
    const int y1 = min(y0 + 1, H_ - 1);
    const float wx1 = sx - (float)x0, wx0 = 1.0f - wx1;
    const float wy1 = sy - (float)y0, wy0 = 1.0f - wy1;

    const f32x4 g00 = *(const f32x4*)&vb[(size_t)(y0 * W_ + x0) * 256 + ch];
    const f32x4 g10 = *(const f32x4*)&vb[(size_t)(y0 * W_ + x1) * 256 + ch];
    const f32x4 g01 = *(const f32x4*)&vb[(size_t)(y1 * W_ + x0) * 256 + ch];
    const f32x4 g11 = *(const f32x4*)&vb[(size_t)(y1 * W_ + x1) * 256 + ch];

    const float w00 = wx0 * wy0, w10 = wx1 * wy0, w01 = wx0 * wy1, w11 = wx1 * wy1;
    const float wp = wt[p];
#pragma unroll
    for (int j = 0; j < 4; ++j)
      acc[j] += wp * (g00[j] * w00 + g01[j] * w01 + g10[j] * w10 + g11[j] * w11);
  }
  *(f32x4*)&mid[(size_t)bq * 256 + ch] = acc;
}

// ---------------------------------------------------------------------------
extern "C" void kernel_launch(void* const* d_in, const int* in_sizes, int n_in,
                              void* d_out, int out_size, void* d_ws, size_t ws_size,
                              hipStream_t stream)
{
  const float* query   = (const float*)d_in[0];
  const float* refp    = (const float*)d_in[1];
  const float* input_f = (const float*)d_in[2];
  const int*   hptr    = (const int*)d_in[3];
  const int*   wptr    = (const int*)d_in[4];
  const float* W_off   = (const float*)d_in[5];
  const float* b_off   = (const float*)d_in[6];
  const float* W_attn  = (const float*)d_in[7];
  const float* b_attn  = (const float*)d_in[8];
  const float* W_val   = (const float*)d_in[9];
  const float* b_val   = (const float*)d_in[10];
  const float* W_out   = (const float*)d_in[11];
  const float* b_out   = (const float*)d_in[12];
  float* out = (float*)d_out;

  const int D   = 256;
  const int BQ  = in_sizes[0] / D;   // 16384
  const int B   = 8;
  const int Q   = BQ / B;            // 2048
  const int BHW = in_sizes[2] / D;   // 80000
  const int HW  = BHW / B;           // 10000

  char* ws = (char*)d_ws;
  float* values = (float*)ws;                                   // 81.92 MB
  size_t o = (size_t)BHW * D * sizeof(float);
  float* offsb  = (float*)(ws + o);  o += (size_t)BQ * 64 * sizeof(float);  // 4.19 MB
  float* logitb = (float*)(ws + o);  o += (size_t)BQ * 32 * sizeof(float);  // 2.10 MB
  float* mid    = (float*)(ws + o);                             // 16.78 MB

  // Pre-swizzled weight overlays on dead regions (256 KB each):
  //  - Bprep_val at head of `mid` (dead until sample writes mid)
  //  - Bprep_out at head of `offsb` (offs dead after sample; prep#2 runs after)
  ushort* Bprep_val = (ushort*)mid;
  ushort* Bprep_out = (ushort*)offsb;

  // 1. values = input_flatten @ W_val + b_val
  prep_wt<<<512, 256, 0, stream>>>(W_val, Bprep_val);
  gemm_split3_n256<64><<<BHW / 64, 256, 0, stream>>>(
      input_f, Bprep_val, b_val, values, BHW);

  // 2. offsets + attention logits
  proj_kernel<<<BQ / 8, 128, 0, stream>>>(
      query, W_off, b_off, W_attn, b_attn, offsb, logitb);

  // 3. softmax + bilinear sampling -> mid
  sample_kernel<<<BQ / 4, 256, 0, stream>>>(
      refp, offsb, logitb, values, mid, hptr, wptr, Q, HW);

  // 4. out = mid @ W_out + b_out
  prep_wt<<<512, 256, 0, stream>>>(W_out, Bprep_out);
  gemm_split3_n256<32><<<BQ / 32, 256, 0, stream>>>(
      mid, Bprep_out, b_out, out, BQ);
}

// Round 11
// 112.679 us; speedup vs baseline: 1.2148x; 1.0863x over previous
//
#include <hip/hip_runtime.h>
#include <hip/hip_bf16.h>
#include <cstdint>

#define NHEADS 8
#define NPOINTS 4

typedef __bf16 bf16x8 __attribute__((ext_vector_type(8)));
typedef float f32x4 __attribute__((ext_vector_type(4)));

#define AS1 __attribute__((address_space(1)))
#define AS3 __attribute__((address_space(3)))

__device__ __forceinline__ ushort f2bf_rn(float x) {
  union { float f; uint32_t u; } c; c.f = x;
  uint32_t r = c.u + 0x7fffu + ((c.u >> 16) & 1u);
  return (ushort)(r >> 16);
}
__device__ __forceinline__ float bf2f(ushort h) {
  union { uint32_t u; float f; } c; c.u = ((uint32_t)h) << 16; return c.f;
}
__device__ __forceinline__ uint pack2(ushort a, ushort b) {
  return (uint)a | ((uint)b << 16);
}

// LDS rows are 128 B = 8 granules of 16 B: granules 0-3 = hi (32 bf16),
// granules 4-7 = lo. Granule index XOR-swizzled by (row&7) (conflict-free,
// verified rounds 3-10). Returns ushort index of granule g0 of `row`.
__device__ __forceinline__ int gidx(int row, int g0) {
  return row * 64 + ((g0 ^ (row & 7)) << 3);
}

// ---------------------------------------------------------------------------
// Split-bf16 (3x MFMA) GEMM, N=256: C[M,256] = A[M,K] @ B[K,256] + bias.
// EXACT r5 structure (best measured: 56 µs, no spill, 0-conflict reads):
// A fp32 -> hi/lo bf16 in LDS (reg-prefetched, single buffer); B staged per
// K-step via global_load_lds from PRE-SWIZZLED Bprep. BK=32.
// NEW (r11): template CBF16 — gemm1 stores C as bf16 (halves C-write traffic
// and makes sample's per-batch working set ~L2-resident).
// LDS = TM*128B (A) + 32 KB (B) => 40 KB @ TM=64.
// ---------------------------------------------------------------------------
template<int TM, bool CBF16>
__global__ __launch_bounds__(256, 3) void gemm_split3_n256(
    const float* __restrict__ A,
    const ushort* __restrict__ Bprep,   // [K/32][16384] pre-swizzled ushorts
    const float* __restrict__ bias, void* __restrict__ Cout,
    int M, int K)
{
  constexpr int MT = TM / 16;
  __shared__ ushort smem[TM * 64 + 16384];   // A region | B region
  const int tid  = threadIdx.x;
  const int lane = tid & 63, wave = tid >> 6;
  const int wn   = wave * 64;
  const int lrow = lane & 15, lgrp = lane >> 4;
  const long brow = (long)blockIdx.x * TM;
  const int NT = K >> 5;
  constexpr int BOFF = TM * 64;              // B region base (ushorts)

  f32x4 acc[MT][4] = {};

  // ---- issue B chunk 0 (async -> LDS) ----
#pragma unroll
  for (int j = 0; j < 8; ++j) {
    const ushort* src = Bprep + (size_t)wave * 512 + (size_t)j * 2048 + (size_t)lane * 8;
    __builtin_amdgcn_global_load_lds((const AS1 void*)src,
                                     (AS3 void*)&smem[BOFF + wave * 512 + j * 2048],
                                     16, 0, 0);
  }

  // ---- A stage-thread mapping + prologue A loads (chunk 0) ----
  float4 areg0, areg1;                 // TM==64: 8 floats; TM==32: areg0 only
  int arow, agq;
  if constexpr (TM == 64) {
    arow = tid >> 2; agq = tid & 3;
    const float* ap = &A[(size_t)(brow + arow) * K + agq * 8];
    areg0 = *(const float4*)ap;
    areg1 = *(const float4*)(ap + 4);
  } else {
    arow = tid >> 3; agq = tid & 7;
    areg0 = *(const float4*)&A[(size_t)(brow + arow) * K + agq * 4];
  }

  for (int t = 0; t < NT; ++t) {
    __syncthreads();   // prev MFMA done with LDS (also drains prefetches)

    // ---- issue B chunk t (t>0; chunk 0 pre-issued) ----
    if (t > 0) {
#pragma unroll
      for (int j = 0; j < 8; ++j) {
        const ushort* src = Bprep + (size_t)t * 16384 + (size_t)wave * 512
                          + (size_t)j * 2048 + (size_t)lane * 8;
        __builtin_amdgcn_global_load_lds((const AS1 void*)src,
                                         (AS3 void*)&smem[BOFF + wave * 512 + j * 2048],
                                         16, 0, 0);
      }
    }

    // ---- convert + write A chunk t from prefetch regs ----
    if constexpr (TM == 64) {
      const float v[8] = {areg0.x, areg0.y, areg0.z, areg0.w,
                          areg1.x, areg1.y, areg1.z, areg1.w};
      ushort h[8], l[8];
#pragma unroll
      for (int j = 0; j < 8; ++j) {
        h[j] = f2bf_rn(v[j]);
        l[j] = f2bf_rn(v[j] - bf2f(h[j]));
      }
      uint4 hv = {pack2(h[0],h[1]), pack2(h[2],h[3]), pack2(h[4],h[5]), pack2(h[6],h[7])};
      uint4 lv = {pack2(l[0],l[1]), pack2(l[2],l[3]), pack2(l[4],l[5]), pack2(l[6],l[7])};
      *(uint4*)&smem[gidx(arow, agq)]     = hv;
      *(uint4*)&smem[gidx(arow, agq + 4)] = lv;
    } else {
      const float v[4] = {areg0.x, areg0.y, areg0.z, areg0.w};
      ushort h[4], l[4];
#pragma unroll
      for (int j = 0; j < 4; ++j) {
        h[j] = f2bf_rn(v[j]);
        l[j] = f2bf_rn(v[j] - bf2f(h[j]));
      }
      const int g = agq >> 1, half = (agq & 1) * 4;
      uint2 hv = {pack2(h[0],h[1]), pack2(h[2],h[3])};
      uint2 lv = {pack2(l[0],l[1]), pack2(l[2],l[3])};
      *(uint2*)&smem[gidx(arow, g)     + half] = hv;
      *(uint2*)&smem[gidx(arow, g + 4) + half] = lv;
    }

    __syncthreads();   // drains B global_load_lds (vm) + A ds_writes (lgkm)

    // ---- prefetch A chunk t+1 (flies under MFMA) ----
    if (t + 1 < NT) {
      if constexpr (TM == 64) {
        const float* ap = &A[(size_t)(brow + arow) * K + (t + 1) * 32 + agq * 8];
        areg0 = *(const float4*)ap;
        areg1 = *(const float4*)(ap + 4);
      } else {
        areg0 = *(const float4*)&A[(size_t)(brow + arow) * K + (t + 1) * 32 + agq * 4];
      }
    }

    // ---- MFMA over chunk t ----
    bf16x8 ah[MT], al[MT];
#pragma unroll
    for (int mt = 0; mt < MT; ++mt) {
      const int r = mt * 16 + lrow;
      ah[mt] = *(const bf16x8*)&smem[gidx(r, lgrp)];
      al[mt] = *(const bf16x8*)&smem[gidx(r, lgrp + 4)];
    }
#pragma unroll
    for (int nt = 0; nt < 4; ++nt) {
      const int r = wn + nt * 16 + lrow;
      const bf16x8 bh = *(const bf16x8*)&smem[BOFF + gidx(r, lgrp)];
      const bf16x8 bl = *(const bf16x8*)&smem[BOFF + gidx(r, lgrp + 4)];
#pragma unroll
      for (int mt = 0; mt < MT; ++mt) {
        acc[mt][nt] = __builtin_amdgcn_mfma_f32_16x16x32_bf16(ah[mt], bh, acc[mt][nt], 0, 0, 0);
        acc[mt][nt] = __builtin_amdgcn_mfma_f32_16x16x32_bf16(ah[mt], bl, acc[mt][nt], 0, 0, 0);
        acc[mt][nt] = __builtin_amdgcn_mfma_f32_16x16x32_bf16(al[mt], bh, acc[mt][nt], 0, 0, 0);
      }
    }
  }

  // ---- epilogue ----
  float bb[4];
#pragma unroll
  for (int nt = 0; nt < 4; ++nt) bb[nt] = bias[wn + nt * 16 + lrow];

  if constexpr (CBF16) {
    // bf16 C: 32-row passes through LDS (ushort, stride 264), full-line stores
    ushort* Cb = (ushort*)Cout;
    ushort* ctu = smem;                       // 32 x 264 ushorts = 16.5 KB
#pragma unroll
    for (int h = 0; h < TM / 32; ++h) {
      __syncthreads();
#pragma unroll
      for (int m2 = 0; m2 < 2; ++m2) {
        const int mt = h * 2 + m2;
        const int lr0 = m2 * 16 + lgrp * 4;
#pragma unroll
        for (int nt = 0; nt < 4; ++nt) {
          const int col = wn + nt * 16 + lrow;
#pragma unroll
          for (int j = 0; j < 4; ++j)
            ctu[(lr0 + j) * 264 + col] = f2bf_rn(acc[mt][nt][j] + bb[nt]);
        }
      }
      __syncthreads();
#pragma unroll
      for (int i = 0; i < 4; ++i) {   // 32 rows * 512B / (256 thr * 16B)
        const int idx = i * 256 + tid, r = idx >> 5, c16 = (idx & 31) * 8;
        *(uint4*)&Cb[(size_t)(brow + h * 32 + r) * 256 + c16] =
            *(const uint4*)&ctu[r * 264 + c16];
      }
    }
  } else {
    // fp32 C: 32-row passes through LDS (float, stride 260), full-line stores
    float* C = (float*)Cout;
    float* ctile = (float*)smem;              // 32 x 260 floats = 33.3 KB
#pragma unroll
    for (int h = 0; h < TM / 32; ++h) {
      __syncthreads();
#pragma unroll
      for (int m2 = 0; m2 < 2; ++m2) {
        const int mt = h * 2 + m2;
        const int lr0 = m2 * 16 + lgrp * 4;
#pragma unroll
        for (int nt = 0; nt < 4; ++nt) {
          const int col = wn + nt * 16 + lrow;
#pragma unroll
          for (int j = 0; j < 4; ++j)
            ctile[(lr0 + j) * 260 + col] = acc[mt][nt][j] + bb[nt];
        }
      }
      __syncthreads();
#pragma unroll
      for (int i = 0; i < 8; ++i) {
        const int idx = i * 256 + tid, r = idx >> 6, c4 = (idx & 63) << 2;
        *(float4*)&C[(size_t)(brow + h * 32 + r) * 256 + c4] =
            *(const float4*)&ctile[r * 260 + c4];
      }
    }
  }
}

// ---------------------------------------------------------------------------
// Weight prep: W fp32 [256][256] -> Bprep (pre-swizzled, K-step-tiled).
// Chunk t (16384 ushorts) is the exact LDS image for K-step t (unchanged).
// ---------------------------------------------------------------------------
__global__ __launch_bounds__(256) void prep_wt(
    const float* __restrict__ W, ushort* __restrict__ Bprep)
{
  const int pg = blockIdx.x * 256 + threadIdx.x;  // 0..131071
  const int t = pg >> 14;
  const int p = pg & 16383;
  const int r = p >> 6;
  const int q = p & 63;
  const int g0 = (q >> 3) ^ (r & 7);              // unswizzled granule
  const int q0 = g0 * 8 + (q & 7);                // unswizzled ushort in row
  const int kk = q0 & 31;
  const float w = W[(size_t)(t * 32 + kk) * 256 + r];
  const ushort hi = f2bf_rn(w);
  Bprep[pg] = (q0 < 32) ? hi : f2bf_rn(w - bf2f(hi));
}

// ---------------------------------------------------------------------------
// Offsets + attention-logits projection (unchanged).
// ---------------------------------------------------------------------------
__global__ __launch_bounds__(128) void proj_kernel(
    const float* __restrict__ query,
    const float* __restrict__ W_off, const float* __restrict__ b_off,
    const float* __restrict__ W_attn, const float* __restrict__ b_attn,
    float* __restrict__ offs, float* __restrict__ logits)
{
  __shared__ float q_lds[8][256];
  const int row0 = blockIdx.x * 8;
  const int tid  = threadIdx.x;

  for (int i = tid; i < 512; i += 128) {
    const int r  = i >> 6;
    const int c4 = (i & 63) << 2;
    *(float4*)&q_lds[r][c4] = *(const float4*)&query[(size_t)(row0 + r) * 256 + c4];
  }
  __syncthreads();
  if (tid >= 96) return;

  float acc[8] = {};
  if (tid < 64) {
    for (int k4 = 0; k4 < 256; k4 += 4) {
      const float w0 = W_off[(k4 + 0) * 64 + tid];
      const float w1 = W_off[(k4 + 1) * 64 + tid];
      const float w2 = W_off[(k4 + 2) * 64 + tid];
      const float w3 = W_off[(k4 + 3) * 64 + tid];
#pragma unroll
      for (int r = 0; r < 8; ++r) {
        float4 q4 = *(const float4*)&q_lds[r][k4];
        acc[r] += q4.x * w0 + q4.y * w1 + q4.z * w2 + q4.w * w3;
      }
    }
    const float bb = b_off[tid];
#pragma unroll
    for (int r = 0; r < 8; ++r)
      offs[(size_t)(row0 + r) * 64 + tid] = acc[r] + bb;
  } else {
    const int j = tid - 64;
    for (int k4 = 0; k4 < 256; k4 += 4) {
      const float w0 = W_attn[(k4 + 0) * 32 + j];
      const float w1 = W_attn[(k4 + 1) * 32 + j];
      const float w2 = W_attn[(k4 + 2) * 32 + j];
      const float w3 = W_attn[(k4 + 3) * 32 + j];
#pragma unroll
      for (int r = 0; r < 8; ++r) {
        float4 q4 = *(const float4*)&q_lds[r][k4];
        acc[r] += q4.x * w0 + q4.y * w1 + q4.z * w2 + q4.w * w3;
      }
    }
    const float bb = b_attn[j];
#pragma unroll
    for (int r = 0; r < 8; ++r)
      logits[(size_t)(row0 + r) * 32 + j] = acc[r] + bb;
  }
}

// ---------------------------------------------------------------------------
// Softmax + bilinear sampling, wave-per-query; values are now bf16
// (8B ushort4 per lane per corner; per-batch working set 5.1 MB ~ L2).
// Blend/weighting in fp32; mid stays fp32.
// ---------------------------------------------------------------------------
__global__ __launch_bounds__(256, 8) void sample_kernel(
    const float* __restrict__ refp,    // [BQ,2]
    const float* __restrict__ offs,    // [BQ,64]  (h*8 + p*2 + c)
    const float* __restrict__ logits,  // [BQ,32]  (h*4 + p)
    const ushort* __restrict__ values, // [B,HW,256] bf16
    float* __restrict__ mid,           // [BQ,256]
    const int* __restrict__ hptr, const int* __restrict__ wptr,
    int Q, int HW)
{
  const int lane = threadIdx.x & 63;
  const int bq   = blockIdx.x * 4 + (threadIdx.x >> 6);
  const int b    = bq / Q;
  const int W_   = *wptr;
  const int H_   = *hptr;
  const int h    = lane >> 3;

  const float l0 = logits[(size_t)bq * 32 + h * 4 + 0];
  const float l1 = logits[(size_t)bq * 32 + h * 4 + 1];
  const float l2 = logits[(size_t)bq * 32 + h * 4 + 2];
  const float l3 = logits[(size_t)bq * 32 + h * 4 + 3];
  const float m  = fmaxf(fmaxf(l0, l1), fmaxf(l2, l3));
  const float e0 = __expf(l0 - m), e1 = __expf(l1 - m);
  const float e2 = __expf(l2 - m), e3 = __expf(l3 - m);
  const float inv = 1.0f / (e0 + e1 + e2 + e3);
  float wt[4] = {e0 * inv, e1 * inv, e2 * inv, e3 * inv};

  const float rx = refp[(size_t)bq * 2 + 0];
  const float ry = refp[(size_t)bq * 2 + 1];
  const ushort* vb = values + (size_t)b * HW * 256;
  const int ch = lane * 4;

  f32x4 acc = {0.f, 0.f, 0.f, 0.f};
#pragma unroll
  for (int p = 0; p < NPOINTS; ++p) {
    float lx = rx + offs[(size_t)bq * 64 + h * 8 + p * 2 + 0];
    float ly = ry + offs[(size_t)bq * 64 + h * 8 + p * 2 + 1];
    lx = fminf(fmaxf(lx, 0.0f), 1.0f);
    ly = fminf(fmaxf(ly, 0.0f), 1.0f);
    const float sx = lx * (float)(W_ - 1);
    const float sy = ly * (float)(H_ - 1);
    int x0 = (int)floorf(sx);
    int y0 = (int)floorf(sy);
    x0 = min(max(x0, 0), W_ - 1);
    y0 = min(max(y0, 0), H_ - 1);
    const int x1 = min(x0 + 1, W_ - 1);
    const int y1 = min(y0 + 1, H_ - 1);
    const float wx1 = sx - (float)x0, wx0 = 1.0f - wx1;
    const float wy1 = sy - (float)y0, wy0 = 1.0f - wy1;

    const ushort4 g00 = *(const ushort4*)&vb[(size_t)(y0 * W_ + x0) * 256 + ch];
    const ushort4 g10 = *(const ushort4*)&vb[(size_t)(y0 * W_ + x1) * 256 + ch];
    const ushort4 g01 = *(const ushort4*)&vb[(size_t)(y1 * W_ + x0) * 256 + ch];
    const ushort4 g11 = *(const ushort4*)&vb[(size_t)(y1 * W_ + x1) * 256 + ch];

    const float w00 = wx0 * wy0, w10 = wx1 * wy0, w01 = wx0 * wy1, w11 = wx1 * wy1;
    const float wp = wt[p];
    const float f00[4] = {bf2f(g00.x), bf2f(g00.y), bf2f(g00.z), bf2f(g00.w)};
    const float f10[4] = {bf2f(g10.x), bf2f(g10.y), bf2f(g10.z), bf2f(g10.w)};
    const float f01[4] = {bf2f(g01.x), bf2f(g01.y), bf2f(g01.z), bf2f(g01.w)};
    const float f11[4] = {bf2f(g11.x), bf2f(g11.y), bf2f(g11.z), bf2f(g11.w)};
#pragma unroll
    for (int j = 0; j < 4; ++j)
      acc[j] += wp * (f00[j] * w00 + f01[j] * w01 + f10[j] * w10 + f11[j] * w11);
  }
  *(f32x4*)&mid[(size_t)bq * 256 + ch] = acc;
}

// ---------------------------------------------------------------------------
extern "C" void kernel_launch(void* const* d_in, const int* in_sizes, int n_in,
                              void* d_out, int out_size, void* d_ws, size_t ws_size,
                              hipStream_t stream)
{
  const float* query   = (const float*)d_in[0];
  const float* refp    = (const float*)d_in[1];
  const float* input_f = (const float*)d_in[2];
  const int*   hptr    = (const int*)d_in[3];
  const int*   wptr    = (const int*)d_in[4];
  const float* W_off   = (const float*)d_in[5];
  const float* b_off   = (const float*)d_in[6];
  const float* W_attn  = (const float*)d_in[7];
  const float* b_attn  = (const float*)d_in[8];
  const float* W_val   = (const float*)d_in[9];
  const float* b_val   = (const float*)d_in[10];
  const float* W_out   = (const float*)d_in[11];
  const float* b_out   = (const float*)d_in[12];
  float* out = (float*)d_out;

  const int D   = 256;
  const int BQ  = in_sizes[0] / D;   // 16384
  const int B   = 8;
  const int Q   = BQ / B;            // 2048
  const int BHW = in_sizes[2] / D;   // 80000
  const int HW  = BHW / B;           // 10000

  char* ws = (char*)d_ws;
  ushort* values = (ushort*)ws;                                 // bf16: 40.96 MB
  size_t o = (size_t)BHW * D * sizeof(ushort);
  float* offsb  = (float*)(ws + o);  o += (size_t)BQ * 64 * sizeof(float);  // 4.19 MB
  float* logitb = (float*)(ws + o);  o += (size_t)BQ * 32 * sizeof(float);  // 2.10 MB
  float* mid    = (float*)(ws + o);                             // 16.78 MB

  // Pre-swizzled weight overlays on dead regions (256 KB each):
  //  - Bprep_val at head of `mid` (dead until sample writes mid)
  //  - Bprep_out at head of `offsb` (offs dead after sample; prep#2 runs after)
  ushort* Bprep_val = (ushort*)mid;
  ushort* Bprep_out = (ushort*)offsb;

  // 1. values(bf16) = input_flatten @ W_val + b_val
  prep_wt<<<512, 256, 0, stream>>>(W_val, Bprep_val);
  gemm_split3_n256<64, true><<<BHW / 64, 256, 0, stream>>>(
      input_f, Bprep_val, b_val, (void*)values, BHW, D);

  // 2. offsets + attention logits
  proj_kernel<<<BQ / 8, 128, 0, stream>>>(
      query, W_off, b_off, W_attn, b_attn, offsb, logitb);

  // 3. softmax + bilinear sampling -> mid (fp32)
  sample_kernel<<<BQ / 4, 256, 0, stream>>>(
      refp, offsb, logitb, values, mid, hptr, wptr, Q, HW);

  // 4. out = mid @ W_out + b_out  (fp32 C)
  prep_wt<<<512, 256, 0, stream>>>(W_out, Bprep_out);
  gemm_split3_n256<32, false><<<BQ / 32, 256, 0, stream>>>(
      mid, Bprep_out, b_out, (void*)out, BQ, D);
}

// Round 13
// 111.581 us; speedup vs baseline: 1.2267x; 1.0098x over previous
//
#include <hip/hip_runtime.h>
#include <hip/hip_bf16.h>
#include <cstdint>

#define NHEADS 8
#define NPOINTS 4

typedef __bf16 bf16x8 __attribute__((ext_vector_type(8)));
typedef float f32x4 __attribute__((ext_vector_type(4)));

#define AS1 __attribute__((address_space(1)))
#define AS3 __attribute__((address_space(3)))

__device__ __forceinline__ ushort f2bf_rn(float x) {
  union { float f; uint32_t u; } c; c.f = x;
  uint32_t r = c.u + 0x7fffu + ((c.u >> 16) & 1u);
  return (ushort)(r >> 16);
}
__device__ __forceinline__ float bf2f(ushort h) {
  union { uint32_t u; float f; } c; c.u = ((uint32_t)h) << 16; return c.f;
}
__device__ __forceinline__ uint pack2(ushort a, ushort b) {
  return (uint)a | ((uint)b << 16);
}

// Each 32-k sub-buffer keeps the verified layout: rows of 128 B = 8 granules
// of 16 B (granules 0-3 = hi 32 bf16, 4-7 = lo), granule index XOR-swizzled
// by (row&7). Conflict-free reads verified rounds 3-11. ushort index.
__device__ __forceinline__ int gidx(int row, int g0) {
  return row * 64 + ((g0 ^ (row & 7)) << 3);
}

// Convert one thread's A share of one 32-k half (fp32 -> hi/lo bf16) -> LDS.
template<int TM>
__device__ __forceinline__ void a_stage_half(
    ushort* Asub, int arow, int agq, float4 r0, float4 r1)
{
  if constexpr (TM == 64) {
    const float v[8] = {r0.x, r0.y, r0.z, r0.w, r1.x, r1.y, r1.z, r1.w};
    ushort h[8], l[8];
#pragma unroll
    for (int j = 0; j < 8; ++j) {
      h[j] = f2bf_rn(v[j]);
      l[j] = f2bf_rn(v[j] - bf2f(h[j]));
    }
    uint4 hv = {pack2(h[0],h[1]), pack2(h[2],h[3]), pack2(h[4],h[5]), pack2(h[6],h[7])};
    uint4 lv = {pack2(l[0],l[1]), pack2(l[2],l[3]), pack2(l[4],l[5]), pack2(l[6],l[7])};
    *(uint4*)&Asub[gidx(arow, agq)]     = hv;
    *(uint4*)&Asub[gidx(arow, agq + 4)] = lv;
  } else {
    const float v[4] = {r0.x, r0.y, r0.z, r0.w};
    ushort h[4], l[4];
#pragma unroll
    for (int j = 0; j < 4; ++j) {
      h[j] = f2bf_rn(v[j]);
      l[j] = f2bf_rn(v[j] - bf2f(h[j]));
    }
    const int g = agq >> 1, half = (agq & 1) * 4;
    uint2 hv = {pack2(h[0],h[1]), pack2(h[2],h[3])};
    uint2 lv = {pack2(l[0],l[1]), pack2(l[2],l[3])};
    *(uint2*)&Asub[gidx(arow, g)     + half] = hv;
    *(uint2*)&Asub[gidx(arow, g + 4) + half] = lv;
  }
}

// ---------------------------------------------------------------------------
// Split-bf16 (3x MFMA) GEMM, N=256: C[M,256] = A[M,K] @ B[K,256] + bias.
// BK=64 (two 32-k sub-chunks per super-step) — halves the barrier count vs
// r5/r11 (per-step stage+drain+barrier tax is the measured stall; m233).
// Per phase: 96 MFMAs cover the A HBM prefetch. Same r5 drain semantics.
// LDS = 2*(TM*128B) A + 2*32KB B = 80 KB @ TM=64 (2 blocks/CU).
// ---------------------------------------------------------------------------
template<int TM, bool CBF16>
__global__ __launch_bounds__(256, 2) void gemm_split3_n256(
    const float* __restrict__ A,
    const ushort* __restrict__ Bprep,   // [K/32][16384] pre-swizzled ushorts
    const float* __restrict__ bias, void* __restrict__ Cout,
    int M, int K)
{
  constexpr int MT = TM / 16;
  constexpr int AH = TM * 64;                 // ushorts per A half-buffer
  constexpr int BOFF = 2 * AH;                // B region base
  __shared__ ushort smem[2 * AH + 2 * 16384];
  const int tid  = threadIdx.x;
  const int lane = tid & 63, wave = tid >> 6;
  const int wn   = wave * 64;
  const int lrow = lane & 15, lgrp = lane >> 4;
  const long brow = (long)blockIdx.x * TM;
  const int NT = K >> 6;                      // super-steps (BK=64)

  f32x4 acc[MT][4] = {};

  // ---- issue B chunks 0,1 (async -> LDS) ----
#pragma unroll
  for (int s = 0; s < 2; ++s)
#pragma unroll
    for (int j = 0; j < 8; ++j)
      __builtin_amdgcn_global_load_lds(
          (const AS1 void*)(Bprep + (size_t)s * 16384 + wave * 512 + j * 2048 + lane * 8),
          (AS3 void*)&smem[BOFF + s * 16384 + wave * 512 + j * 2048], 16, 0, 0);

  // ---- A stage-thread mapping + prologue loads (super-step 0) ----
  int arow, agq;
  if constexpr (TM == 64) { arow = tid >> 2; agq = tid & 3; }
  else                    { arow = tid >> 3; agq = tid & 7; }
  const float* Abase = &A[(size_t)(brow + arow) * K];

  float4 ar0, ar1, ar2, ar3;                  // halves: {ar0,ar1}, {ar2,ar3}
  if constexpr (TM == 64) {
    ar0 = *(const float4*)(Abase + agq * 8);
    ar1 = *(const float4*)(Abase + agq * 8 + 4);
    ar2 = *(const float4*)(Abase + 32 + agq * 8);
    ar3 = *(const float4*)(Abase + 32 + agq * 8 + 4);
  } else {
    ar0 = *(const float4*)(Abase + agq * 4);
    ar2 = *(const float4*)(Abase + 32 + agq * 4);
  }

  for (int t = 0; t < NT; ++t) {
    __syncthreads();   // prev MFMA done with LDS

    // ---- issue B chunks 2t, 2t+1 (t>0; pre-issued for t=0) ----
    if (t > 0) {
#pragma unroll
      for (int s = 0; s < 2; ++s)
#pragma unroll
        for (int j = 0; j < 8; ++j)
          __builtin_amdgcn_global_load_lds(
              (const AS1 void*)(Bprep + (size_t)(2 * t + s) * 16384 + wave * 512 + j * 2048 + lane * 8),
              (AS3 void*)&smem[BOFF + s * 16384 + wave * 512 + j * 2048], 16, 0, 0);
    }

    // ---- convert + write A(t) both halves from prefetch regs ----
    a_stage_half<TM>(smem,      arow, agq, ar0, ar1);
    a_stage_half<TM>(smem + AH, arow, agq, ar2, ar3);

    __syncthreads();   // drains B glds (vm) + A ds_writes (lgkm)

    // ---- prefetch A(t+1), flies under the 96-MFMA phase ----
    if (t + 1 < NT) {
      const float* ap = Abase + (t + 1) * 64;
      if constexpr (TM == 64) {
        ar0 = *(const float4*)(ap + agq * 8);
        ar1 = *(const float4*)(ap + agq * 8 + 4);
        ar2 = *(const float4*)(ap + 32 + agq * 8);
        ar3 = *(const float4*)(ap + 32 + agq * 8 + 4);
      } else {
        ar0 = *(const float4*)(ap + agq * 4);
        ar2 = *(const float4*)(ap + 32 + agq * 4);
      }
    }

    // ---- MFMA over both 32-k halves ----
#pragma unroll
    for (int s = 0; s < 2; ++s) {
      const ushort* Asub = smem + s * AH;
      const ushort* Bsub = smem + BOFF + s * 16384;
      bf16x8 ah[MT], al[MT];
#pragma unroll
      for (int mt = 0; mt < MT; ++mt) {
        const int r = mt * 16 + lrow;
        ah[mt] = *(const bf16x8*)&Asub[gidx(r, lgrp)];
        al[mt] = *(const bf16x8*)&Asub[gidx(r, lgrp + 4)];
      }
#pragma unroll
      for (int nt = 0; nt < 4; ++nt) {
        const int r = wn + nt * 16 + lrow;
        const bf16x8 bh = *(const bf16x8*)&Bsub[gidx(r, lgrp)];
        const bf16x8 bl = *(const bf16x8*)&Bsub[gidx(r, lgrp + 4)];
#pragma unroll
        for (int mt = 0; mt < MT; ++mt) {
          acc[mt][nt] = __builtin_amdgcn_mfma_f32_16x16x32_bf16(ah[mt], bh, acc[mt][nt], 0, 0, 0);
          acc[mt][nt] = __builtin_amdgcn_mfma_f32_16x16x32_bf16(ah[mt], bl, acc[mt][nt], 0, 0, 0);
          acc[mt][nt] = __builtin_amdgcn_mfma_f32_16x16x32_bf16(al[mt], bh, acc[mt][nt], 0, 0, 0);
        }
      }
    }
  }

  // ---- epilogue ----
  float bb[4];
#pragma unroll
  for (int nt = 0; nt < 4; ++nt) bb[nt] = bias[wn + nt * 16 + lrow];

  if constexpr (CBF16) {
    ushort* Cb = (ushort*)Cout;
    ushort* ctu = smem;                       // 32 x 264 ushorts = 16.5 KB
#pragma unroll
    for (int h = 0; h < TM / 32; ++h) {
      __syncthreads();
#pragma unroll
      for (int m2 = 0; m2 < 2; ++m2) {
        const int mt = h * 2 + m2;
        const int lr0 = m2 * 16 + lgrp * 4;
#pragma unroll
        for (int nt = 0; nt < 4; ++nt) {
          const int col = wn + nt * 16 + lrow;
#pragma unroll
          for (int j = 0; j < 4; ++j)
            ctu[(lr0 + j) * 264 + col] = f2bf_rn(acc[mt][nt][j] + bb[nt]);
        }
      }
      __syncthreads();
#pragma unroll
      for (int i = 0; i < 4; ++i) {
        const int idx = i * 256 + tid, r = idx >> 5, c16 = (idx & 31) * 8;
        *(uint4*)&Cb[(size_t)(brow + h * 32 + r) * 256 + c16] =
            *(const uint4*)&ctu[r * 264 + c16];
      }
    }
  } else {
    float* C = (float*)Cout;
    float* ctile = (float*)smem;              // 32 x 260 floats = 33.3 KB
#pragma unroll
    for (int h = 0; h < TM / 32; ++h) {
      __syncthreads();
#pragma unroll
      for (int m2 = 0; m2 < 2; ++m2) {
        const int mt = h * 2 + m2;
        const int lr0 = m2 * 16 + lgrp * 4;
#pragma unroll
        for (int nt = 0; nt < 4; ++nt) {
          const int col = wn + nt * 16 + lrow;
#pragma unroll
          for (int j = 0; j < 4; ++j)
            ctile[(lr0 + j) * 260 + col] = acc[mt][nt][j] + bb[nt];
        }
      }
      __syncthreads();
#pragma unroll
      for (int i = 0; i < 8; ++i) {
        const int idx = i * 256 + tid, r = idx >> 6, c4 = (idx & 63) << 2;
        *(float4*)&C[(size_t)(brow + h * 32 + r) * 256 + c4] =
            *(const float4*)&ctile[r * 260 + c4];
      }
    }
  }
}

// ---------------------------------------------------------------------------
// Weight prep, both weights fused: W fp32 [256][256] -> Bprep (pre-swizzled,
// 32-k-chunk-tiled LDS images; layout unchanged from rounds 5-11).
// Each Bprep is 8 chunks x 16384 ushorts = 256 KB (hi+lo planes).
// ---------------------------------------------------------------------------
__global__ __launch_bounds__(256) void prep_wt2(
    const float* __restrict__ Wv, const float* __restrict__ Wo,
    ushort* __restrict__ Bv, ushort* __restrict__ Bo)
{
  const int gid = blockIdx.x * 256 + threadIdx.x;  // 0..262143
  const float* W = (gid < 131072) ? Wv : Wo;
  ushort* Bp     = (gid < 131072) ? Bv : Bo;
  const int pg = gid & 131071;
  const int t = pg >> 14;
  const int p = pg & 16383;
  const int r = p >> 6;
  const int q = p & 63;
  const int g0 = (q >> 3) ^ (r & 7);
  const int q0 = g0 * 8 + (q & 7);
  const int kk = q0 & 31;
  const float w = W[(size_t)(t * 32 + kk) * 256 + r];
  const ushort hi = f2bf_rn(w);
  Bp[pg] = (q0 < 32) ? hi : f2bf_rn(w - bf2f(hi));
}

// ---------------------------------------------------------------------------
// Offsets + attention-logits projection (unchanged).
// ---------------------------------------------------------------------------
__global__ __launch_bounds__(128) void proj_kernel(
    const float* __restrict__ query,
    const float* __restrict__ W_off, const float* __restrict__ b_off,
    const float* __restrict__ W_attn, const float* __restrict__ b_attn,
    float* __restrict__ offs, float* __restrict__ logits)
{
  __shared__ float q_lds[8][256];
  const int row0 = blockIdx.x * 8;
  const int tid  = threadIdx.x;

  for (int i = tid; i < 512; i += 128) {
    const int r  = i >> 6;
    const int c4 = (i & 63) << 2;
    *(float4*)&q_lds[r][c4] = *(const float4*)&query[(size_t)(row0 + r) * 256 + c4];
  }
  __syncthreads();
  if (tid >= 96) return;

  float acc[8] = {};
  if (tid < 64) {
    for (int k4 = 0; k4 < 256; k4 += 4) {
      const float w0 = W_off[(k4 + 0) * 64 + tid];
      const float w1 = W_off[(k4 + 1) * 64 + tid];
      const float w2 = W_off[(k4 + 2) * 64 + tid];
      const float w3 = W_off[(k4 + 3) * 64 + tid];
#pragma unroll
      for (int r = 0; r < 8; ++r) {
        float4 q4 = *(const float4*)&q_lds[r][k4];
        acc[r] += q4.x * w0 + q4.y * w1 + q4.z * w2 + q4.w * w3;
      }
    }
    const float bb = b_off[tid];
#pragma unroll
    for (int r = 0; r < 8; ++r)
      offs[(size_t)(row0 + r) * 64 + tid] = acc[r] + bb;
  } else {
    const int j = tid - 64;
    for (int k4 = 0; k4 < 256; k4 += 4) {
      const float w0 = W_attn[(k4 + 0) * 32 + j];
      const float w1 = W_attn[(k4 + 1) * 32 + j];
      const float w2 = W_attn[(k4 + 2) * 32 + j];
      const float w3 = W_attn[(k4 + 3) * 32 + j];
#pragma unroll
      for (int r = 0; r < 8; ++r) {
        float4 q4 = *(const float4*)&q_lds[r][k4];
        acc[r] += q4.x * w0 + q4.y * w1 + q4.z * w2 + q4.w * w3;
      }
    }
    const float bb = b_attn[j];
#pragma unroll
    for (int r = 0; r < 8; ++r)
      logits[(size_t)(row0 + r) * 32 + j] = acc[r] + bb;
  }
}

// ---------------------------------------------------------------------------
// Softmax + bilinear sampling, wave-per-query; bf16 values (unchanged).
// ---------------------------------------------------------------------------
__global__ __launch_bounds__(256, 8) void sample_kernel(
    const float* __restrict__ refp,    // [BQ,2]
    const float* __restrict__ offs,    // [BQ,64]  (h*8 + p*2 + c)
    const float* __restrict__ logits,  // [BQ,32]  (h*4 + p)
    const ushort* __restrict__ values, // [B,HW,256] bf16
    float* __restrict__ mid,           // [BQ,256]
    const int* __restrict__ hptr, const int* __restrict__ wptr,
    int Q, int HW)
{
  const int lane = threadIdx.x & 63;
  const int bq   = blockIdx.x * 4 + (threadIdx.x >> 6);
  const int b    = bq / Q;
  const int W_   = *wptr;
  const int H_   = *hptr;
  const int h    = lane >> 3;

  const float l0 = logits[(size_t)bq * 32 + h * 4 + 0];
  const float l1 = logits[(size_t)bq * 32 + h * 4 + 1];
  const float l2 = logits[(size_t)bq * 32 + h * 4 + 2];
  const float l3 = logits[(size_t)bq * 32 + h * 4 + 3];
  const float m  = fmaxf(fmaxf(l0, l1), fmaxf(l2, l3));
  const float e0 = __expf(l0 - m), e1 = __expf(l1 - m);
  const float e2 = __expf(l2 - m), e3 = __expf(l3 - m);
  const float inv = 1.0f / (e0 + e1 + e2 + e3);
  float wt[4] = {e0 * inv, e1 * inv, e2 * inv, e3 * inv};

  const float rx = refp[(size_t)bq * 2 + 0];
  const float ry = refp[(size_t)bq * 2 + 1];
  const ushort* vb = values + (size_t)b * HW * 256;
  const int ch = lane * 4;

  f32x4 acc = {0.f, 0.f, 0.f, 0.f};
#pragma unroll
  for (int p = 0; p < NPOINTS; ++p) {
    float lx = rx + offs[(size_t)bq * 64 + h * 8 + p * 2 + 0];
    float ly = ry + offs[(size_t)bq * 64 + h * 8 + p * 2 + 1];
    lx = fminf(fmaxf(lx, 0.0f), 1.0f);
    ly = fminf(fmaxf(ly, 0.0f), 1.0f);
    const float sx = lx * (float)(W_ - 1);
    const float sy = ly * (float)(H_ - 1);
    int x0 = (int)floorf(sx);
    int y0 = (int)floorf(sy);
    x0 = min(max(x0, 0), W_ - 1);
    y0 = min(max(y0, 0), H_ - 1);
    const int x1 = min(x0 + 1, W_ - 1);
    const int y1 = min(y0 + 1, H_ - 1);
    const float wx1 = sx - (float)x0, wx0 = 1.0f - wx1;
    const float wy1 = sy - (float)y0, wy0 = 1.0f - wy1;

    const ushort4 g00 = *(const ushort4*)&vb[(size_t)(y0 * W_ + x0) * 256 + ch];
    const ushort4 g10 = *(const ushort4*)&vb[(size_t)(y0 * W_ + x1) * 256 + ch];
    const ushort4 g01 = *(const ushort4*)&vb[(size_t)(y1 * W_ + x0) * 256 + ch];
    const ushort4 g11 = *(const ushort4*)&vb[(size_t)(y1 * W_ + x1) * 256 + ch];

    const float w00 = wx0 * wy0, w10 = wx1 * wy0, w01 = wx0 * wy1, w11 = wx1 * wy1;
    const float wp = wt[p];
    const float f00[4] = {bf2f(g00.x), bf2f(g00.y), bf2f(g00.z), bf2f(g00.w)};
    const float f10[4] = {bf2f(g10.x), bf2f(g10.y), bf2f(g10.z), bf2f(g10.w)};
    const float f01[4] = {bf2f(g01.x), bf2f(g01.y), bf2f(g01.z), bf2f(g01.w)};
    const float f11[4] = {bf2f(g11.x), bf2f(g11.y), bf2f(g11.z), bf2f(g11.w)};
#pragma unroll
    for (int j = 0; j < 4; ++j)
      acc[j] += wp * (f00[j] * w00 + f01[j] * w01 + f10[j] * w10 + f11[j] * w11);
  }
  *(f32x4*)&mid[(size_t)bq * 256 + ch] = acc;
}

// ---------------------------------------------------------------------------
extern "C" void kernel_launch(void* const* d_in, const int* in_sizes, int n_in,
                              void* d_out, int out_size, void* d_ws, size_t ws_size,
                              hipStream_t stream)
{
  const float* query   = (const float*)d_in[0];
  const float* refp    = (const float*)d_in[1];
  const float* input_f = (const float*)d_in[2];
  const int*   hptr    = (const int*)d_in[3];
  const int*   wptr    = (const int*)d_in[4];
  const float* W_off   = (const float*)d_in[5];
  const float* b_off   = (const float*)d_in[6];
  const float* W_attn  = (const float*)d_in[7];
  const float* b_attn  = (const float*)d_in[8];
  const float* W_val   = (const float*)d_in[9];
  const float* b_val   = (const float*)d_in[10];
  const float* W_out   = (const float*)d_in[11];
  const float* b_out   = (const float*)d_in[12];
  float* out = (float*)d_out;

  const int D   = 256;
  const int BQ  = in_sizes[0] / D;   // 16384
  const int B   = 8;
  const int Q   = BQ / B;            // 2048
  const int BHW = in_sizes[2] / D;   // 80000
  const int HW  = BHW / B;           // 10000

  char* ws = (char*)d_ws;
  ushort* values = (ushort*)ws;                                 // bf16: 40.96 MB
  size_t o = (size_t)BHW * D * sizeof(ushort);
  float* offsb  = (float*)(ws + o);  o += (size_t)BQ * 64 * sizeof(float);  // 4.19 MB
  float* logitb = (float*)(ws + o);  o += (size_t)BQ * 32 * sizeof(float);  // 2.10 MB
  float* mid    = (float*)(ws + o);  o += (size_t)BQ * D * sizeof(float);   // 16.78 MB
  // Each Bprep = (D/32) chunks x 16384 ushorts = 256 KB (r12 bug: was 128 KB
  // -> Bprep_out overlapped Bprep_val's chunks 4-7; corrupted both GEMMs).
  ushort* Bprep_val = (ushort*)(ws + o);  o += (size_t)(D / 32) * 16384 * sizeof(ushort);
  ushort* Bprep_out = (ushort*)(ws + o);  o += (size_t)(D / 32) * 16384 * sizeof(ushort);

  // 0. both weight preps in one launch
  prep_wt2<<<1024, 256, 0, stream>>>(W_val, W_out, Bprep_val, Bprep_out);

  // 1. values(bf16) = input_flatten @ W_val + b_val
  gemm_split3_n256<64, true><<<BHW / 64, 256, 0, stream>>>(
      input_f, Bprep_val, b_val, (void*)values, BHW, D);

  // 2. offsets + attention logits
  proj_kernel<<<BQ / 8, 128, 0, stream>>>(
      query, W_off, b_off, W_attn, b_attn, offsb, logitb);

  // 3. softmax + bilinear sampling -> mid (fp32)
  sample_kernel<<<BQ / 4, 256, 0, stream>>>(
      refp, offsb, logitb, values, mid, hptr, wptr, Q, HW);

  // 4. out = mid @ W_out + b_out  (fp32 C)
  gemm_split3_n256<32, false><<<BQ / 32, 256, 0, stream>>>(
      mid, Bprep_out, b_out, (void*)out, BQ, D);
}

// Round 14
// 106.650 us; speedup vs baseline: 1.2834x; 1.0462x over previous
//
#include <hip/hip_runtime.h>
#include <hip/hip_bf16.h>
#include <cstdint>

#define NHEADS 8
#define NPOINTS 4

typedef __bf16 bf16x8 __attribute__((ext_vector_type(8)));
typedef float f32x4 __attribute__((ext_vector_type(4)));

#define AS1 __attribute__((address_space(1)))
#define AS3 __attribute__((address_space(3)))

__device__ __forceinline__ ushort f2bf_rn(float x) {
  union { float f; uint32_t u; } c; c.f = x;
  uint32_t r = c.u + 0x7fffu + ((c.u >> 16) & 1u);
  return (ushort)(r >> 16);
}
__device__ __forceinline__ float bf2f(ushort h) {
  union { uint32_t u; float f; } c; c.u = ((uint32_t)h) << 16; return c.f;
}
__device__ __forceinline__ uint pack2(ushort a, ushort b) {
  return (uint)a | ((uint)b << 16);
}

// LDS rows are 128 B = 8 granules of 16 B. For B: granules 0-3 = hi plane,
// 4-7 = lo plane. For A (r14): only granules 0-3 used (pure-bf16 A).
// Granule index XOR-swizzled by (row&7) — conflict-free (verified r3-r13).
__device__ __forceinline__ int gidx(int row, int g0) {
  return row * 64 + ((g0 ^ (row & 7)) << 3);
}

// ---------------------------------------------------------------------------
// 2-term split GEMM, N=256: C[M,256] = A[M,K] @ B[K,256] + bias.
// r14: A is PURE bf16 (hi plane only — error ~6e-4 sigma, within the bf16
// output-comparison budget); B stays split hi/lo. Per fragment pair:
// 2 MFMAs (ah*bh + ah*bl). MFMA work -33%, A-convert -66%, A ds_write -50%
// vs the 3-term r11 kernel; LDS geometry identical (40 KB, lo-A unused).
// Structure = r11 exact (best measured): BK=32, single rotating B buffer
// via global_load_lds from pre-swizzled Bprep, A reg-prefetch pipeline.
// ---------------------------------------------------------------------------
template<int TM, bool CBF16>
__global__ __launch_bounds__(256, 3) void gemm_split2_n256(
    const float* __restrict__ A,
    const ushort* __restrict__ Bprep,   // [K/32][16384] pre-swizzled ushorts
    const float* __restrict__ bias, void* __restrict__ Cout,
    int M, int K)
{
  constexpr int MT = TM / 16;
  __shared__ ushort smem[TM * 64 + 16384];   // A region | B region
  const int tid  = threadIdx.x;
  const int lane = tid & 63, wave = tid >> 6;
  const int wn   = wave * 64;
  const int lrow = lane & 15, lgrp = lane >> 4;
  const long brow = (long)blockIdx.x * TM;
  const int NT = K >> 5;
  constexpr int BOFF = TM * 64;              // B region base (ushorts)

  f32x4 acc[MT][4] = {};

  // ---- issue B chunk 0 (async -> LDS) ----
#pragma unroll
  for (int j = 0; j < 8; ++j) {
    const ushort* src = Bprep + (size_t)wave * 512 + (size_t)j * 2048 + (size_t)lane * 8;
    __builtin_amdgcn_global_load_lds((const AS1 void*)src,
                                     (AS3 void*)&smem[BOFF + wave * 512 + j * 2048],
                                     16, 0, 0);
  }

  // ---- A stage-thread mapping + prologue A loads (chunk 0) ----
  float4 areg0, areg1;
  int arow, agq;
  if constexpr (TM == 64) {
    arow = tid >> 2; agq = tid & 3;
    const float* ap = &A[(size_t)(brow + arow) * K + agq * 8];
    areg0 = *(const float4*)ap;
    areg1 = *(const float4*)(ap + 4);
  } else {
    arow = tid >> 3; agq = tid & 7;
    areg0 = *(const float4*)&A[(size_t)(brow + arow) * K + agq * 4];
  }

  for (int t = 0; t < NT; ++t) {
    __syncthreads();   // prev MFMA done with LDS (also drains prefetches)

    // ---- issue B chunk t (t>0; chunk 0 pre-issued) ----
    if (t > 0) {
#pragma unroll
      for (int j = 0; j < 8; ++j) {
        const ushort* src = Bprep + (size_t)t * 16384 + (size_t)wave * 512
                          + (size_t)j * 2048 + (size_t)lane * 8;
        __builtin_amdgcn_global_load_lds((const AS1 void*)src,
                                         (AS3 void*)&smem[BOFF + wave * 512 + j * 2048],
                                         16, 0, 0);
      }
    }

    // ---- convert (hi only) + write A chunk t from prefetch regs ----
    if constexpr (TM == 64) {
      const float v[8] = {areg0.x, areg0.y, areg0.z, areg0.w,
                          areg1.x, areg1.y, areg1.z, areg1.w};
      ushort h[8];
#pragma unroll
      for (int j = 0; j < 8; ++j) h[j] = f2bf_rn(v[j]);
      uint4 hv = {pack2(h[0],h[1]), pack2(h[2],h[3]), pack2(h[4],h[5]), pack2(h[6],h[7])};
      *(uint4*)&smem[gidx(arow, agq)] = hv;
    } else {
      const float v[4] = {areg0.x, areg0.y, areg0.z, areg0.w};
      ushort h[4];
#pragma unroll
      for (int j = 0; j < 4; ++j) h[j] = f2bf_rn(v[j]);
      const int g = agq >> 1, half = (agq & 1) * 4;
      uint2 hv = {pack2(h[0],h[1]), pack2(h[2],h[3])};
      *(uint2*)&smem[gidx(arow, g) + half] = hv;
    }

    __syncthreads();   // drains B global_load_lds (vm) + A ds_writes (lgkm)

    // ---- prefetch A chunk t+1 (flies under MFMA) ----
    if (t + 1 < NT) {
      if constexpr (TM == 64) {
        const float* ap = &A[(size_t)(brow + arow) * K + (t + 1) * 32 + agq * 8];
        areg0 = *(const float4*)ap;
        areg1 = *(const float4*)(ap + 4);
      } else {
        areg0 = *(const float4*)&A[(size_t)(brow + arow) * K + (t + 1) * 32 + agq * 4];
      }
    }

    // ---- MFMA over chunk t: 2 terms (ah*bh + ah*bl) ----
    bf16x8 ah[MT];
#pragma unroll
    for (int mt = 0; mt < MT; ++mt)
      ah[mt] = *(const bf16x8*)&smem[gidx(mt * 16 + lrow, lgrp)];
#pragma unroll
    for (int nt = 0; nt < 4; ++nt) {
      const int r = wn + nt * 16 + lrow;
      const bf16x8 bh = *(const bf16x8*)&smem[BOFF + gidx(r, lgrp)];
      const bf16x8 bl = *(const bf16x8*)&smem[BOFF + gidx(r, lgrp + 4)];
#pragma unroll
      for (int mt = 0; mt < MT; ++mt) {
        acc[mt][nt] = __builtin_amdgcn_mfma_f32_16x16x32_bf16(ah[mt], bh, acc[mt][nt], 0, 0, 0);
        acc[mt][nt] = __builtin_amdgcn_mfma_f32_16x16x32_bf16(ah[mt], bl, acc[mt][nt], 0, 0, 0);
      }
    }
  }

  // ---- epilogue ----
  float bb[4];
#pragma unroll
  for (int nt = 0; nt < 4; ++nt) bb[nt] = bias[wn + nt * 16 + lrow];

  if constexpr (CBF16) {
    ushort* Cb = (ushort*)Cout;
    ushort* ctu = smem;                       // 32 x 264 ushorts = 16.5 KB
#pragma unroll
    for (int h = 0; h < TM / 32; ++h) {
      __syncthreads();
#pragma unroll
      for (int m2 = 0; m2 < 2; ++m2) {
        const int mt = h * 2 + m2;
        const int lr0 = m2 * 16 + lgrp * 4;
#pragma unroll
        for (int nt = 0; nt < 4; ++nt) {
          const int col = wn + nt * 16 + lrow;
#pragma unroll
          for (int j = 0; j < 4; ++j)
            ctu[(lr0 + j) * 264 + col] = f2bf_rn(acc[mt][nt][j] + bb[nt]);
        }
      }
      __syncthreads();
#pragma unroll
      for (int i = 0; i < 4; ++i) {
        const int idx = i * 256 + tid, r = idx >> 5, c16 = (idx & 31) * 8;
        *(uint4*)&Cb[(size_t)(brow + h * 32 + r) * 256 + c16] =
            *(const uint4*)&ctu[r * 264 + c16];
      }
    }
  } else {
    float* C = (float*)Cout;
    float* ctile = (float*)smem;              // 16 x 260 floats (TM=32 path)
#pragma unroll
    for (int h = 0; h < MT; ++h) {
      __syncthreads();
#pragma unroll
      for (int nt = 0; nt < 4; ++nt) {
        const int col = wn + nt * 16 + lrow;
#pragma unroll
        for (int j = 0; j < 4; ++j)
          ctile[(lgrp * 4 + j) * 260 + col] = acc[h][nt][j] + bb[nt];
      }
      __syncthreads();
#pragma unroll
      for (int i = 0; i < 4; ++i) {   // 16 rows * 64 float4 / 256 threads
        const int idx = i * 256 + tid, r = idx >> 6, c4 = (idx & 63) << 2;
        *(float4*)&C[(size_t)(brow + h * 16 + r) * 256 + c4] =
            *(const float4*)&ctile[r * 260 + c4];
      }
    }
  }
}

// ---------------------------------------------------------------------------
// Weight prep, both weights fused: W fp32 [256][256] -> Bprep (pre-swizzled,
// 32-k-chunk-tiled LDS images, hi+lo planes; layout unchanged r5-r13).
// Each Bprep is 8 chunks x 16384 ushorts = 256 KB.
// ---------------------------------------------------------------------------
__global__ __launch_bounds__(256) void prep_wt2(
    const float* __restrict__ Wv, const float* __restrict__ Wo,
    ushort* __restrict__ Bv, ushort* __restrict__ Bo)
{
  const int gid = blockIdx.x * 256 + threadIdx.x;  // 0..262143
  const float* W = (gid < 131072) ? Wv : Wo;
  ushort* Bp     = (gid < 131072) ? Bv : Bo;
  const int pg = gid & 131071;
  const int t = pg >> 14;
  const int p = pg & 16383;
  const int r = p >> 6;
  const int q = p & 63;
  const int g0 = (q >> 3) ^ (r & 7);
  const int q0 = g0 * 8 + (q & 7);
  const int kk = q0 & 31;
  const float w = W[(size_t)(t * 32 + kk) * 256 + r];
  const ushort hi = f2bf_rn(w);
  Bp[pg] = (q0 < 32) ? hi : f2bf_rn(w - bf2f(hi));
}

// ---------------------------------------------------------------------------
// Offsets + attention-logits projection (unchanged).
// ---------------------------------------------------------------------------
__global__ __launch_bounds__(128) void proj_kernel(
    const float* __restrict__ query,
    const float* __restrict__ W_off, const float* __restrict__ b_off,
    const float* __restrict__ W_attn, const float* __restrict__ b_attn,
    float* __restrict__ offs, float* __restrict__ logits)
{
  __shared__ float q_lds[8][256];
  const int row0 = blockIdx.x * 8;
  const int tid  = threadIdx.x;

  for (int i = tid; i < 512; i += 128) {
    const int r  = i >> 6;
    const int c4 = (i & 63) << 2;
    *(float4*)&q_lds[r][c4] = *(const float4*)&query[(size_t)(row0 + r) * 256 + c4];
  }
  __syncthreads();
  if (tid >= 96) return;

  float acc[8] = {};
  if (tid < 64) {
    for (int k4 = 0; k4 < 256; k4 += 4) {
      const float w0 = W_off[(k4 + 0) * 64 + tid];
      const float w1 = W_off[(k4 + 1) * 64 + tid];
      const float w2 = W_off[(k4 + 2) * 64 + tid];
      const float w3 = W_off[(k4 + 3) * 64 + tid];
#pragma unroll
      for (int r = 0; r < 8; ++r) {
        float4 q4 = *(const float4*)&q_lds[r][k4];
        acc[r] += q4.x * w0 + q4.y * w1 + q4.z * w2 + q4.w * w3;
      }
    }
    const float bb = b_off[tid];
#pragma unroll
    for (int r = 0; r < 8; ++r)
      offs[(size_t)(row0 + r) * 64 + tid] = acc[r] + bb;
  } else {
    const int j = tid - 64;
    for (int k4 = 0; k4 < 256; k4 += 4) {
      const float w0 = W_attn[(k4 + 0) * 32 + j];
      const float w1 = W_attn[(k4 + 1) * 32 + j];
      const float w2 = W_attn[(k4 + 2) * 32 + j];
      const float w3 = W_attn[(k4 + 3) * 32 + j];
#pragma unroll
      for (int r = 0; r < 8; ++r) {
        float4 q4 = *(const float4*)&q_lds[r][k4];
        acc[r] += q4.x * w0 + q4.y * w1 + q4.z * w2 + q4.w * w3;
      }
    }
    const float bb = b_attn[j];
#pragma unroll
    for (int r = 0; r < 8; ++r)
      logits[(size_t)(row0 + r) * 32 + j] = acc[r] + bb;
  }
}

// ---------------------------------------------------------------------------
// Softmax + bilinear sampling, wave-per-query; bf16 values (unchanged).
// ---------------------------------------------------------------------------
__global__ __launch_bounds__(256, 8) void sample_kernel(
    const float* __restrict__ refp,    // [BQ,2]
    const float* __restrict__ offs,    // [BQ,64]  (h*8 + p*2 + c)
    const float* __restrict__ logits,  // [BQ,32]  (h*4 + p)
    const ushort* __restrict__ values, // [B,HW,256] bf16
    float* __restrict__ mid,           // [BQ,256]
    const int* __restrict__ hptr, const int* __restrict__ wptr,
    int Q, int HW)
{
  const int lane = threadIdx.x & 63;
  const int bq   = blockIdx.x * 4 + (threadIdx.x >> 6);
  const int b    = bq / Q;
  const int W_   = *wptr;
  const int H_   = *hptr;
  const int h    = lane >> 3;

  const float l0 = logits[(size_t)bq * 32 + h * 4 + 0];
  const float l1 = logits[(size_t)bq * 32 + h * 4 + 1];
  const float l2 = logits[(size_t)bq * 32 + h * 4 + 2];
  const float l3 = logits[(size_t)bq * 32 + h * 4 + 3];
  const float m  = fmaxf(fmaxf(l0, l1), fmaxf(l2, l3));
  const float e0 = __expf(l0 - m), e1 = __expf(l1 - m);
  const float e2 = __expf(l2 - m), e3 = __expf(l3 - m);
  const float inv = 1.0f / (e0 + e1 + e2 + e3);
  float wt[4] = {e0 * inv, e1 * inv, e2 * inv, e3 * inv};

  const float rx = refp[(size_t)bq * 2 + 0];
  const float ry = refp[(size_t)bq * 2 + 1];
  const ushort* vb = values + (size_t)b * HW * 256;
  const int ch = lane * 4;

  f32x4 acc = {0.f, 0.f, 0.f, 0.f};
#pragma unroll
  for (int p = 0; p < NPOINTS; ++p) {
    float lx = rx + offs[(size_t)bq * 64 + h * 8 + p * 2 + 0];
    float ly = ry + offs[(size_t)bq * 64 + h * 8 + p * 2 + 1];
    lx = fminf(fmaxf(lx, 0.0f), 1.0f);
    ly = fminf(fmaxf(ly, 0.0f), 1.0f);
    const float sx = lx * (float)(W_ - 1);
    const float sy = ly * (float)(H_ - 1);
    int x0 = (int)floorf(sx);
    int y0 = (int)floorf(sy);
    x0 = min(max(x0, 0), W_ - 1);
    y0 = min(max(y0, 0), H_ - 1);
    const int x1 = min(x0 + 1, W_ - 1);
    const int y1 = min(y0 + 1, H_ - 1);
    const float wx1 = sx - (float)x0, wx0 = 1.0f - wx1;
    const float wy1 = sy - (float)y0, wy0 = 1.0f - wy1;

    const ushort4 g00 = *(const ushort4*)&vb[(size_t)(y0 * W_ + x0) * 256 + ch];
    const ushort4 g10 = *(const ushort4*)&vb[(size_t)(y0 * W_ + x1) * 256 + ch];
    const ushort4 g01 = *(const ushort4*)&vb[(size_t)(y1 * W_ + x0) * 256 + ch];
    const ushort4 g11 = *(const ushort4*)&vb[(size_t)(y1 * W_ + x1) * 256 + ch];

    const float w00 = wx0 * wy0, w10 = wx1 * wy0, w01 = wx0 * wy1, w11 = wx1 * wy1;
    const float wp = wt[p];
    const float f00[4] = {bf2f(g00.x), bf2f(g00.y), bf2f(g00.z), bf2f(g00.w)};
    const float f10[4] = {bf2f(g10.x), bf2f(g10.y), bf2f(g10.z), bf2f(g10.w)};
    const float f01[4] = {bf2f(g01.x), bf2f(g01.y), bf2f(g01.z), bf2f(g01.w)};
    const float f11[4] = {bf2f(g11.x), bf2f(g11.y), bf2f(g11.z), bf2f(g11.w)};
#pragma unroll
    for (int j = 0; j < 4; ++j)
      acc[j] += wp * (f00[j] * w00 + f01[j] * w01 + f10[j] * w10 + f11[j] * w11);
  }
  *(f32x4*)&mid[(size_t)bq * 256 + ch] = acc;
}

// ---------------------------------------------------------------------------
extern "C" void kernel_launch(void* const* d_in, const int* in_sizes, int n_in,
                              void* d_out, int out_size, void* d_ws, size_t ws_size,
                              hipStream_t stream)
{
  const float* query   = (const float*)d_in[0];
  const float* refp    = (const float*)d_in[1];
  const float* input_f = (const float*)d_in[2];
  const int*   hptr    = (const int*)d_in[3];
  const int*   wptr    = (const int*)d_in[4];
  const float* W_off   = (const float*)d_in[5];
  const float* b_off   = (const float*)d_in[6];
  const float* W_attn  = (const float*)d_in[7];
  const float* b_attn  = (const float*)d_in[8];
  const float* W_val   = (const float*)d_in[9];
  const float* b_val   = (const float*)d_in[10];
  const float* W_out   = (const float*)d_in[11];
  const float* b_out   = (const float*)d_in[12];
  float* out = (float*)d_out;

  const int D   = 256;
  const int BQ  = in_sizes[0] / D;   // 16384
  const int B   = 8;
  const int Q   = BQ / B;            // 2048
  const int BHW = in_sizes[2] / D;   // 80000
  const int HW  = BHW / B;           // 10000

  char* ws = (char*)d_ws;
  ushort* values = (ushort*)ws;                                 // bf16: 40.96 MB
  size_t o = (size_t)BHW * D * sizeof(ushort);
  float* offsb  = (float*)(ws + o);  o += (size_t)BQ * 64 * sizeof(float);
  float* logitb = (float*)(ws + o);  o += (size_t)BQ * 32 * sizeof(float);
  float* mid    = (float*)(ws + o);  o += (size_t)BQ * D * sizeof(float);
  // Each Bprep = (D/32) chunks x 16384 ushorts = 256 KB.
  ushort* Bprep_val = (ushort*)(ws + o);  o += (size_t)(D / 32) * 16384 * sizeof(ushort);
  ushort* Bprep_out = (ushort*)(ws + o);  o += (size_t)(D / 32) * 16384 * sizeof(ushort);

  // 0. both weight preps in one launch
  prep_wt2<<<1024, 256, 0, stream>>>(W_val, W_out, Bprep_val, Bprep_out);

  // 1. values(bf16) = input_flatten @ W_val + b_val
  gemm_split2_n256<64, true><<<BHW / 64, 256, 0, stream>>>(
      input_f, Bprep_val, b_val, (void*)values, BHW, D);

  // 2. offsets + attention logits
  proj_kernel<<<BQ / 8, 128, 0, stream>>>(
      query, W_off, b_off, W_attn, b_attn, offsb, logitb);

  // 3. softmax + bilinear sampling -> mid (fp32)
  sample_kernel<<<BQ / 4, 256, 0, stream>>>(
      refp, offsb, logitb, values, mid, hptr, wptr, Q, HW);

  // 4. out = mid @ W_out + b_out  (fp32 C)
  gemm_split2_n256<32, false><<<BQ / 32, 256, 0, stream>>>(
      mid, Bprep_out, b_out, (void*)out, BQ, D);
}

// Round 15
// 92.732 us; speedup vs baseline: 1.4761x; 1.1501x over previous
//
#include <hip/hip_runtime.h>
#include <hip/hip_bf16.h>
#include <cstdint>

#define NHEADS 8
#define NPOINTS 4

typedef __bf16 bf16x8 __attribute__((ext_vector_type(8)));
typedef float f32x4 __attribute__((ext_vector_type(4)));

#define AS1 __attribute__((address_space(1)))
#define AS3 __attribute__((address_space(3)))

__device__ __forceinline__ ushort f2bf_rn(float x) {
  union { float f; uint32_t u; } c; c.f = x;
  uint32_t r = c.u + 0x7fffu + ((c.u >> 16) & 1u);
  return (ushort)(r >> 16);
}
__device__ __forceinline__ float bf2f(ushort h) {
  union { uint32_t u; float f; } c; c.u = ((uint32_t)h) << 16; return c.f;
}
__device__ __forceinline__ uint pack2(ushort a, ushort b) {
  return (uint)a | ((uint)b << 16);
}

// r15 LDS layout: pure-bf16 tiles, rows of 64 B = 4 granules of 16 B
// (8 bf16 = one k-segment). Granule POSITION = segment ^ fr(row) with
// fr(row) = (row>>1)&3 -> 16-lane read groups alias banks only 2-way
// (free, m136). Read/write/Bprep all share this involution.
__device__ __forceinline__ int fr(int row) { return (row >> 1) & 3; }
__device__ __forceinline__ int aidx(int row, int gpos) { return row * 32 + gpos * 8; }

// ---------------------------------------------------------------------------
// Pure-bf16 GEMM, N=256: C[M,256] = A[M,K] @ B[K,256] + bias.
// r15: B hi-only (pure bf16) AND double-buffered -> B(t+1) glds issued a
// full step (16 MFMAs + A-convert, ~400cy) before the sync that drains
// them (r5-r14 exposed that latency every step: issue->drain gap ~40 ops).
// A also double-buffered (4 KB each). LDS = 2*(TM*64B) + 2*16KB = 40 KB
// @ TM=64 -> 4 blocks/CU. One barrier per K-step (BK=32).
// ---------------------------------------------------------------------------
template<int TM, bool CBF16>
__global__ __launch_bounds__(256, 4) void gemm_bf16_n256(
    const float* __restrict__ A,
    const ushort* __restrict__ Bprep,   // [K/32][8192] pre-swizzled ushorts
    const float* __restrict__ bias, void* __restrict__ Cout,
    int M, int K)
{
  constexpr int MT = TM / 16;
  constexpr int AH = TM * 32;                 // ushorts per A buffer
  constexpr int BH = 8192;                    // ushorts per B buffer (16 KB)
  __shared__ ushort smem[2 * AH + 2 * BH];
  const int tid  = threadIdx.x;
  const int lane = tid & 63, wave = tid >> 6;
  const int wn   = wave * 64;
  const int lrow = lane & 15, lgrp = lane >> 4;
  const long brow = (long)blockIdx.x * TM;
  const int NT = K >> 5;

  f32x4 acc[MT][4] = {};

  int arow, as_;                              // A stage mapping
  if constexpr (TM == 64) { arow = tid >> 2; as_ = tid & 3; }
  else                    { arow = tid >> 3; as_ = tid & 7; }
  const float* Abase = &A[(size_t)(brow + arow) * K];

  ushort* Acur = smem;
  ushort* Anxt = smem + AH;
  ushort* Bcur = smem + 2 * AH;
  ushort* Bnxt = smem + 2 * AH + BH;

  // ---- prologue: B(0) glds + A(0) stage, one barrier ----
#pragma unroll
  for (int i = 0; i < 4; ++i)
    __builtin_amdgcn_global_load_lds(
        (const AS1 void*)(Bprep + wave * 2048 + (lane + 64 * i) * 8),
        (AS3 void*)(Bcur + wave * 2048 + (lane + 64 * i) * 8), 16, 0, 0);
  if constexpr (TM == 64) {
    const float* ap = Abase + as_ * 8;
    float4 a0 = *(const float4*)ap, a1 = *(const float4*)(ap + 4);
    const float v[8] = {a0.x, a0.y, a0.z, a0.w, a1.x, a1.y, a1.z, a1.w};
    ushort h[8];
#pragma unroll
    for (int j = 0; j < 8; ++j) h[j] = f2bf_rn(v[j]);
    uint4 hv = {pack2(h[0],h[1]), pack2(h[2],h[3]), pack2(h[4],h[5]), pack2(h[6],h[7])};
    *(uint4*)&Acur[aidx(arow, as_ ^ fr(arow))] = hv;
  } else {
    const int g = as_ >> 1, half = (as_ & 1) * 4;
    float4 a0 = *(const float4*)(Abase + g * 8 + half);
    ushort h[4] = {f2bf_rn(a0.x), f2bf_rn(a0.y), f2bf_rn(a0.z), f2bf_rn(a0.w)};
    uint2 hv = {pack2(h[0],h[1]), pack2(h[2],h[3])};
    *(uint2*)&Acur[aidx(arow, g ^ fr(arow)) + half] = hv;
  }
  __syncthreads();

  for (int t = 0; t < NT; ++t) {
    const bool more = (t + 1 < NT);

    // ---- issue B(t+1) glds into the other buffer (1-step distance) ----
    if (more) {
#pragma unroll
      for (int i = 0; i < 4; ++i)
        __builtin_amdgcn_global_load_lds(
            (const AS1 void*)(Bprep + (size_t)(t + 1) * BH + wave * 2048 + (lane + 64 * i) * 8),
            (AS3 void*)(Bnxt + wave * 2048 + (lane + 64 * i) * 8), 16, 0, 0);
    }

    // ---- A(t+1) reg prefetch ----
    float4 a0 = {}, a1 = {};
    if (more) {
      if constexpr (TM == 64) {
        const float* ap = Abase + (t + 1) * 32 + as_ * 8;
        a0 = *(const float4*)ap;
        a1 = *(const float4*)(ap + 4);
      } else {
        const int g = as_ >> 1, half = (as_ & 1) * 4;
        a0 = *(const float4*)(Abase + (t + 1) * 32 + g * 8 + half);
      }
    }

    // ---- MFMA(t): 1 MFMA per (mt,nt), pure bf16 ----
    bf16x8 ah[MT];
#pragma unroll
    for (int mt = 0; mt < MT; ++mt) {
      const int r = mt * 16 + lrow;
      ah[mt] = *(const bf16x8*)&Acur[aidx(r, lgrp ^ fr(r))];
    }
#pragma unroll
    for (int nt = 0; nt < 4; ++nt) {
      const int r = wn + nt * 16 + lrow;
      const bf16x8 b = *(const bf16x8*)&Bcur[aidx(r, lgrp ^ fr(r))];
#pragma unroll
      for (int mt = 0; mt < MT; ++mt)
        acc[mt][nt] = __builtin_amdgcn_mfma_f32_16x16x32_bf16(ah[mt], b, acc[mt][nt], 0, 0, 0);
    }

    // ---- convert + ds_write A(t+1) into the other buffer ----
    if (more) {
      if constexpr (TM == 64) {
        const float v[8] = {a0.x, a0.y, a0.z, a0.w, a1.x, a1.y, a1.z, a1.w};
        ushort h[8];
#pragma unroll
        for (int j = 0; j < 8; ++j) h[j] = f2bf_rn(v[j]);
        uint4 hv = {pack2(h[0],h[1]), pack2(h[2],h[3]), pack2(h[4],h[5]), pack2(h[6],h[7])};
        *(uint4*)&Anxt[aidx(arow, as_ ^ fr(arow))] = hv;
      } else {
        const int g = as_ >> 1, half = (as_ & 1) * 4;
        ushort h[4] = {f2bf_rn(a0.x), f2bf_rn(a0.y), f2bf_rn(a0.z), f2bf_rn(a0.w)};
        uint2 hv = {pack2(h[0],h[1]), pack2(h[2],h[3])};
        *(uint2*)&Anxt[aidx(arow, g ^ fr(arow)) + half] = hv;
      }
    }

    __syncthreads();   // drains B(t+1) glds (issued ~400cy ago) + A writes
    ushort* tp;
    tp = Acur; Acur = Anxt; Anxt = tp;
    tp = Bcur; Bcur = Bnxt; Bnxt = tp;
  }

  // ---- epilogue ----
  float bb[4];
#pragma unroll
  for (int nt = 0; nt < 4; ++nt) bb[nt] = bias[wn + nt * 16 + lrow];

  if constexpr (CBF16) {
    ushort* Cb = (ushort*)Cout;
    ushort* ctu = smem;                       // 32 x 264 ushorts = 16.5 KB
#pragma unroll
    for (int h = 0; h < TM / 32; ++h) {
      __syncthreads();
#pragma unroll
      for (int m2 = 0; m2 < 2; ++m2) {
        const int mt = h * 2 + m2;
        const int lr0 = m2 * 16 + lgrp * 4;
#pragma unroll
        for (int nt = 0; nt < 4; ++nt) {
          const int col = wn + nt * 16 + lrow;
#pragma unroll
          for (int j = 0; j < 4; ++j)
            ctu[(lr0 + j) * 264 + col] = f2bf_rn(acc[mt][nt][j] + bb[nt]);
        }
      }
      __syncthreads();
#pragma unroll
      for (int i = 0; i < 4; ++i) {
        const int idx = i * 256 + tid, r = idx >> 5, c16 = (idx & 31) * 8;
        *(uint4*)&Cb[(size_t)(brow + h * 32 + r) * 256 + c16] =
            *(const uint4*)&ctu[r * 264 + c16];
      }
    }
  } else {
    float* C = (float*)Cout;
    float* ctile = (float*)smem;              // 16 x 260 floats (TM=32 path)
#pragma unroll
    for (int h = 0; h < MT; ++h) {
      __syncthreads();
#pragma unroll
      for (int nt = 0; nt < 4; ++nt) {
        const int col = wn + nt * 16 + lrow;
#pragma unroll
        for (int j = 0; j < 4; ++j)
          ctile[(lgrp * 4 + j) * 260 + col] = acc[h][nt][j] + bb[nt];
      }
      __syncthreads();
#pragma unroll
      for (int i = 0; i < 4; ++i) {   // 16 rows * 64 float4 / 256 threads
        const int idx = i * 256 + tid, r = idx >> 6, c4 = (idx & 63) << 2;
        *(float4*)&C[(size_t)(brow + h * 16 + r) * 256 + c4] =
            *(const float4*)&ctile[r * 260 + c4];
      }
    }
  }
}

// ---------------------------------------------------------------------------
// Weight prep, both weights fused: W fp32 [256][256] -> Bprep bf16 hi-only,
// pre-swizzled 32-k-chunk LDS images (64-B rows, pos = seg ^ fr(row)).
// Each Bprep = 8 chunks x 8192 ushorts = 128 KB.
// ---------------------------------------------------------------------------
__global__ __launch_bounds__(256) void prep_wt2(
    const float* __restrict__ Wv, const float* __restrict__ Wo,
    ushort* __restrict__ Bv, ushort* __restrict__ Bo)
{
  const int gid = blockIdx.x * 256 + threadIdx.x;  // 0..131071
  const float* W = (gid < 65536) ? Wv : Wo;
  ushort* Bp     = (gid < 65536) ? Bv : Bo;
  const int pg = gid & 65535;
  const int t = pg >> 13;
  const int p = pg & 8191;
  const int r = p >> 5;
  const int q = p & 31;
  const int gpos = q >> 3;
  const int j = q & 7;
  const int g0 = gpos ^ ((r >> 1) & 3);            // un-swizzled k-segment
  const int k = t * 32 + g0 * 8 + j;
  Bp[pg] = f2bf_rn(W[(size_t)k * 256 + r]);
}

// ---------------------------------------------------------------------------
// Offsets + attention-logits projection (unchanged).
// ---------------------------------------------------------------------------
__global__ __launch_bounds__(128) void proj_kernel(
    const float* __restrict__ query,
    const float* __restrict__ W_off, const float* __restrict__ b_off,
    const float* __restrict__ W_attn, const float* __restrict__ b_attn,
    float* __restrict__ offs, float* __restrict__ logits)
{
  __shared__ float q_lds[8][256];
  const int row0 = blockIdx.x * 8;
  const int tid  = threadIdx.x;

  for (int i = tid; i < 512; i += 128) {
    const int r  = i >> 6;
    const int c4 = (i & 63) << 2;
    *(float4*)&q_lds[r][c4] = *(const float4*)&query[(size_t)(row0 + r) * 256 + c4];
  }
  __syncthreads();
  if (tid >= 96) return;

  float acc[8] = {};
  if (tid < 64) {
    for (int k4 = 0; k4 < 256; k4 += 4) {
      const float w0 = W_off[(k4 + 0) * 64 + tid];
      const float w1 = W_off[(k4 + 1) * 64 + tid];
      const float w2 = W_off[(k4 + 2) * 64 + tid];
      const float w3 = W_off[(k4 + 3) * 64 + tid];
#pragma unroll
      for (int r = 0; r < 8; ++r) {
        float4 q4 = *(const float4*)&q_lds[r][k4];
        acc[r] += q4.x * w0 + q4.y * w1 + q4.z * w2 + q4.w * w3;
      }
    }
    const float bb = b_off[tid];
#pragma unroll
    for (int r = 0; r < 8; ++r)
      offs[(size_t)(row0 + r) * 64 + tid] = acc[r] + bb;
  } else {
    const int j = tid - 64;
    for (int k4 = 0; k4 < 256; k4 += 4) {
      const float w0 = W_attn[(k4 + 0) * 32 + j];
      const float w1 = W_attn[(k4 + 1) * 32 + j];
      const float w2 = W_attn[(k4 + 2) * 32 + j];
      const float w3 = W_attn[(k4 + 3) * 32 + j];
#pragma unroll
      for (int r = 0; r < 8; ++r) {
        float4 q4 = *(const float4*)&q_lds[r][k4];
        acc[r] += q4.x * w0 + q4.y * w1 + q4.z * w2 + q4.w * w3;
      }
    }
    const float bb = b_attn[j];
#pragma unroll
    for (int r = 0; r < 8; ++r)
      logits[(size_t)(row0 + r) * 32 + j] = acc[r] + bb;
  }
}

// ---------------------------------------------------------------------------
// Softmax + bilinear sampling, wave-per-query; bf16 values (unchanged).
// ---------------------------------------------------------------------------
__global__ __launch_bounds__(256, 8) void sample_kernel(
    const float* __restrict__ refp,    // [BQ,2]
    const float* __restrict__ offs,    // [BQ,64]  (h*8 + p*2 + c)
    const float* __restrict__ logits,  // [BQ,32]  (h*4 + p)
    const ushort* __restrict__ values, // [B,HW,256] bf16
    float* __restrict__ mid,           // [BQ,256]
    const int* __restrict__ hptr, const int* __restrict__ wptr,
    int Q, int HW)
{
  const int lane = threadIdx.x & 63;
  const int bq   = blockIdx.x * 4 + (threadIdx.x >> 6);
  const int b    = bq / Q;
  const int W_   = *wptr;
  const int H_   = *hptr;
  const int h    = lane >> 3;

  const float l0 = logits[(size_t)bq * 32 + h * 4 + 0];
  const float l1 = logits[(size_t)bq * 32 + h * 4 + 1];
  const float l2 = logits[(size_t)bq * 32 + h * 4 + 2];
  const float l3 = logits[(size_t)bq * 32 + h * 4 + 3];
  const float m  = fmaxf(fmaxf(l0, l1), fmaxf(l2, l3));
  const float e0 = __expf(l0 - m), e1 = __expf(l1 - m);
  const float e2 = __expf(l2 - m), e3 = __expf(l3 - m);
  const float inv = 1.0f / (e0 + e1 + e2 + e3);
  float wt[4] = {e0 * inv, e1 * inv, e2 * inv, e3 * inv};

  const float rx = refp[(size_t)bq * 2 + 0];
  const float ry = refp[(size_t)bq * 2 + 1];
  const ushort* vb = values + (size_t)b * HW * 256;
  const int ch = lane * 4;

  f32x4 acc = {0.f, 0.f, 0.f, 0.f};
#pragma unroll
  for (int p = 0; p < NPOINTS; ++p) {
    float lx = rx + offs[(size_t)bq * 64 + h * 8 + p * 2 + 0];
    float ly = ry + offs[(size_t)bq * 64 + h * 8 + p * 2 + 1];
    lx = fminf(fmaxf(lx, 0.0f), 1.0f);
    ly = fminf(fmaxf(ly, 0.0f), 1.0f);
    const float sx = lx * (float)(W_ - 1);
    const float sy = ly * (float)(H_ - 1);
    int x0 = (int)floorf(sx);
    int y0 = (int)floorf(sy);
    x0 = min(max(x0, 0), W_ - 1);
    y0 = min(max(y0, 0), H_ - 1);
    const int x1 = min(x0 + 1, W_ - 1);
    const int y1 = min(y0 + 1, H_ - 1);
    const float wx1 = sx - (float)x0, wx0 = 1.0f - wx1;
    const float wy1 = sy - (float)y0, wy0 = 1.0f - wy1;

    const ushort4 g00 = *(const ushort4*)&vb[(size_t)(y0 * W_ + x0) * 256 + ch];
    const ushort4 g10 = *(const ushort4*)&vb[(size_t)(y0 * W_ + x1) * 256 + ch];
    const ushort4 g01 = *(const ushort4*)&vb[(size_t)(y1 * W_ + x0) * 256 + ch];
    const ushort4 g11 = *(const ushort4*)&vb[(size_t)(y1 * W_ + x1) * 256 + ch];

    const float w00 = wx0 * wy0, w10 = wx1 * wy0, w01 = wx0 * wy1, w11 = wx1 * wy1;
    const float wp = wt[p];
    const float f00[4] = {bf2f(g00.x), bf2f(g00.y), bf2f(g00.z), bf2f(g00.w)};
    const float f10[4] = {bf2f(g10.x), bf2f(g10.y), bf2f(g10.z), bf2f(g10.w)};
    const float f01[4] = {bf2f(g01.x), bf2f(g01.y), bf2f(g01.z), bf2f(g01.w)};
    const float f11[4] = {bf2f(g11.x), bf2f(g11.y), bf2f(g11.z), bf2f(g11.w)};
#pragma unroll
    for (int j = 0; j < 4; ++j)
      acc[j] += wp * (f00[j] * w00 + f01[j] * w01 + f10[j] * w10 + f11[j] * w11);
  }
  *(f32x4*)&mid[(size_t)bq * 256 + ch] = acc;
}

// ---------------------------------------------------------------------------
extern "C" void kernel_launch(void* const* d_in, const int* in_sizes, int n_in,
                              void* d_out, int out_size, void* d_ws, size_t ws_size,
                              hipStream_t stream)
{
  const float* query   = (const float*)d_in[0];
  const float* refp    = (const float*)d_in[1];
  const float* input_f = (const float*)d_in[2];
  const int*   hptr    = (const int*)d_in[3];
  const int*   wptr    = (const int*)d_in[4];
  const float* W_off   = (const float*)d_in[5];
  const float* b_off   = (const float*)d_in[6];
  const float* W_attn  = (const float*)d_in[7];
  const float* b_attn  = (const float*)d_in[8];
  const float* W_val   = (const float*)d_in[9];
  const float* b_val   = (const float*)d_in[10];
  const float* W_out   = (const float*)d_in[11];
  const float* b_out   = (const float*)d_in[12];
  float* out = (float*)d_out;

  const int D   = 256;
  const int BQ  = in_sizes[0] / D;   // 16384
  const int B   = 8;
  const int Q   = BQ / B;            // 2048
  const int BHW = in_sizes[2] / D;   // 80000
  const int HW  = BHW / B;           // 10000

  char* ws = (char*)d_ws;
  ushort* values = (ushort*)ws;                                 // bf16: 40.96 MB
  size_t o = (size_t)BHW * D * sizeof(ushort);
  float* offsb  = (float*)(ws + o);  o += (size_t)BQ * 64 * sizeof(float);
  float* logitb = (float*)(ws + o);  o += (size_t)BQ * 32 * sizeof(float);
  float* mid    = (float*)(ws + o);  o += (size_t)BQ * D * sizeof(float);
  // Each Bprep = (D/32) chunks x 8192 ushorts = 128 KB (bf16 hi-only).
  ushort* Bprep_val = (ushort*)(ws + o);  o += (size_t)(D / 32) * 8192 * sizeof(ushort);
  ushort* Bprep_out = (ushort*)(ws + o);  o += (size_t)(D / 32) * 8192 * sizeof(ushort);

  // 0. both weight preps in one launch
  prep_wt2<<<512, 256, 0, stream>>>(W_val, W_out, Bprep_val, Bprep_out);

  // 1. values(bf16) = input_flatten @ W_val + b_val
  gemm_bf16_n256<64, true><<<BHW / 64, 256, 0, stream>>>(
      input_f, Bprep_val, b_val, (void*)values, BHW, D);

  // 2. offsets + attention logits
  proj_kernel<<<BQ / 8, 128, 0, stream>>>(
      query, W_off, b_off, W_attn, b_attn, offsb, logitb);

  // 3. softmax + bilinear sampling -> mid (fp32)
  sample_kernel<<<BQ / 4, 256, 0, stream>>>(
      refp, offsb, logitb, values, mid, hptr, wptr, Q, HW);

  // 4. out = mid @ W_out + b_out  (fp32 C)
  gemm_bf16_n256<32, false><<<BQ / 32, 256, 0, stream>>>(
      mid, Bprep_out, b_out, (void*)out, BQ, D);
}

// Round 16
// 84.272 us; speedup vs baseline: 1.6242x; 1.1004x over previous
//
#include <hip/hip_runtime.h>
#include <hip/hip_bf16.h>
#include <cstdint>

#define NHEADS 8
#define NPOINTS 4

typedef __bf16 bf16x8 __attribute__((ext_vector_type(8)));
typedef float f32x4 __attribute__((ext_vector_type(4)));

#define AS1 __attribute__((address_space(1)))
#define AS3 __attribute__((address_space(3)))

__device__ __forceinline__ ushort f2bf_rn(float x) {
  union { float f; uint32_t u; } c; c.f = x;
  uint32_t r = c.u + 0x7fffu + ((c.u >> 16) & 1u);
  return (ushort)(r >> 16);
}
__device__ __forceinline__ float bf2f(ushort h) {
  union { uint32_t u; float f; } c; c.u = ((uint32_t)h) << 16; return c.f;
}
__device__ __forceinline__ uint pack2(ushort a, ushort b) {
  return (uint)a | ((uint)b << 16);
}

// LDS layout (r15, verified): pure-bf16 tiles, rows of 64 B = 4 granules of
// 16 B (8 bf16 = one k-segment). Granule POSITION = segment ^ fr(row),
// fr(row) = (row>>1)&3 -> 2-way bank aliasing only (free, m136).
__device__ __forceinline__ int fr(int row) { return (row >> 1) & 3; }
__device__ __forceinline__ int aidx(int row, int gpos) { return row * 32 + gpos * 8; }

// ---------------------------------------------------------------------------
// Pure-bf16 GEMM, N=256: C[M,256] = A[M,K] @ B[K,256] + bias.
// r15 structure (verified 92.7 total): B hi-only bf16, A+B double-buffered,
// B(t+1) glds issued a full step before the draining sync. BK=32.
// r16: template ABF16 — gemm2's A (mid) arrives as bf16, so its A-stage is
// a pure uint2 copy (no fp32 load, no convert). Precision-neutral: gemm2
// rounded A to bf16 anyway.
// LDS = 2*(TM*64B) + 2*16KB = 40 KB @ TM=64 -> 4 blocks/CU.
// ---------------------------------------------------------------------------
template<int TM, bool CBF16, bool ABF16>
__global__ __launch_bounds__(256, 4) void gemm_bf16_n256(
    const void* __restrict__ Ain,
    const ushort* __restrict__ Bprep,   // [K/32][8192] pre-swizzled ushorts
    const float* __restrict__ bias, void* __restrict__ Cout,
    int M, int K)
{
  constexpr int MT = TM / 16;
  constexpr int AH = TM * 32;                 // ushorts per A buffer
  constexpr int BH = 8192;                    // ushorts per B buffer (16 KB)
  __shared__ ushort smem[2 * AH + 2 * BH];
  const int tid  = threadIdx.x;
  const int lane = tid & 63, wave = tid >> 6;
  const int wn   = wave * 64;
  const int lrow = lane & 15, lgrp = lane >> 4;
  const long brow = (long)blockIdx.x * TM;
  const int NT = K >> 5;

  const float*  Af = (const float*)Ain;
  const ushort* A16 = (const ushort*)Ain;

  f32x4 acc[MT][4] = {};

  int arow, as_;                              // A stage mapping
  if constexpr (TM == 64) { arow = tid >> 2; as_ = tid & 3; }
  else                    { arow = tid >> 3; as_ = tid & 7; }

  ushort* Acur = smem;
  ushort* Anxt = smem + AH;
  ushort* Bcur = smem + 2 * AH;
  ushort* Bnxt = smem + 2 * AH + BH;

  // ---- prologue: B(0) glds + A(0) stage, one barrier ----
#pragma unroll
  for (int i = 0; i < 4; ++i)
    __builtin_amdgcn_global_load_lds(
        (const AS1 void*)(Bprep + wave * 2048 + (lane + 64 * i) * 8),
        (AS3 void*)(Bcur + wave * 2048 + (lane + 64 * i) * 8), 16, 0, 0);
  if constexpr (ABF16) {
    uint2 av = *(const uint2*)&A16[(size_t)(brow + arow) * K + as_ * 4];
    const int g = as_ >> 1, half = (as_ & 1) * 4;
    *(uint2*)&Acur[aidx(arow, g ^ fr(arow)) + half] = av;
  } else if constexpr (TM == 64) {
    const float* ap = &Af[(size_t)(brow + arow) * K] + as_ * 8;
    float4 a0 = *(const float4*)ap, a1 = *(const float4*)(ap + 4);
    const float v[8] = {a0.x, a0.y, a0.z, a0.w, a1.x, a1.y, a1.z, a1.w};
    ushort h[8];
#pragma unroll
    for (int j = 0; j < 8; ++j) h[j] = f2bf_rn(v[j]);
    uint4 hv = {pack2(h[0],h[1]), pack2(h[2],h[3]), pack2(h[4],h[5]), pack2(h[6],h[7])};
    *(uint4*)&Acur[aidx(arow, as_ ^ fr(arow))] = hv;
  } else {
    const int g = as_ >> 1, half = (as_ & 1) * 4;
    float4 a0 = *(const float4*)&Af[(size_t)(brow + arow) * K + g * 8 + half];
    ushort h[4] = {f2bf_rn(a0.x), f2bf_rn(a0.y), f2bf_rn(a0.z), f2bf_rn(a0.w)};
    uint2 hv = {pack2(h[0],h[1]), pack2(h[2],h[3])};
    *(uint2*)&Acur[aidx(arow, g ^ fr(arow)) + half] = hv;
  }
  __syncthreads();

  for (int t = 0; t < NT; ++t) {
    const bool more = (t + 1 < NT);

    // ---- issue B(t+1) glds into the other buffer (1-step distance) ----
    if (more) {
#pragma unroll
      for (int i = 0; i < 4; ++i)
        __builtin_amdgcn_global_load_lds(
            (const AS1 void*)(Bprep + (size_t)(t + 1) * BH + wave * 2048 + (lane + 64 * i) * 8),
            (AS3 void*)(Bnxt + wave * 2048 + (lane + 64 * i) * 8), 16, 0, 0);
    }

    // ---- A(t+1) reg prefetch ----
    float4 a0 = {}, a1 = {};
    uint2 au = {};
    if (more) {
      if constexpr (ABF16) {
        au = *(const uint2*)&A16[(size_t)(brow + arow) * K + (t + 1) * 32 + as_ * 4];
      } else if constexpr (TM == 64) {
        const float* ap = &Af[(size_t)(brow + arow) * K] + (t + 1) * 32 + as_ * 8;
        a0 = *(const float4*)ap;
        a1 = *(const float4*)(ap + 4);
      } else {
        const int g = as_ >> 1, half = (as_ & 1) * 4;
        a0 = *(const float4*)&Af[(size_t)(brow + arow) * K + (t + 1) * 32 + g * 8 + half];
      }
    }

    // ---- MFMA(t): 1 MFMA per (mt,nt), pure bf16 ----
    bf16x8 ah[MT];
#pragma unroll
    for (int mt = 0; mt < MT; ++mt) {
      const int r = mt * 16 + lrow;
      ah[mt] = *(const bf16x8*)&Acur[aidx(r, lgrp ^ fr(r))];
    }
#pragma unroll
    for (int nt = 0; nt < 4; ++nt) {
      const int r = wn + nt * 16 + lrow;
      const bf16x8 b = *(const bf16x8*)&Bcur[aidx(r, lgrp ^ fr(r))];
#pragma unroll
      for (int mt = 0; mt < MT; ++mt)
        acc[mt][nt] = __builtin_amdgcn_mfma_f32_16x16x32_bf16(ah[mt], b, acc[mt][nt], 0, 0, 0);
    }

    // ---- convert + ds_write A(t+1) into the other buffer ----
    if (more) {
      if constexpr (ABF16) {
        const int g = as_ >> 1, half = (as_ & 1) * 4;
        *(uint2*)&Anxt[aidx(arow, g ^ fr(arow)) + half] = au;
      } else if constexpr (TM == 64) {
        const float v[8] = {a0.x, a0.y, a0.z, a0.w, a1.x, a1.y, a1.z, a1.w};
        ushort h[8];
#pragma unroll
        for (int j = 0; j < 8; ++j) h[j] = f2bf_rn(v[j]);
        uint4 hv = {pack2(h[0],h[1]), pack2(h[2],h[3]), pack2(h[4],h[5]), pack2(h[6],h[7])};
        *(uint4*)&Anxt[aidx(arow, as_ ^ fr(arow))] = hv;
      } else {
        const int g = as_ >> 1, half = (as_ & 1) * 4;
        ushort h[4] = {f2bf_rn(a0.x), f2bf_rn(a0.y), f2bf_rn(a0.z), f2bf_rn(a0.w)};
        uint2 hv = {pack2(h[0],h[1]), pack2(h[2],h[3])};
        *(uint2*)&Anxt[aidx(arow, g ^ fr(arow)) + half] = hv;
      }
    }

    __syncthreads();   // drains B(t+1) glds (issued ~400cy ago) + A writes
    ushort* tp;
    tp = Acur; Acur = Anxt; Anxt = tp;
    tp = Bcur; Bcur = Bnxt; Bnxt = tp;
  }

  // ---- epilogue ----
  float bb[4];
#pragma unroll
  for (int nt = 0; nt < 4; ++nt) bb[nt] = bias[wn + nt * 16 + lrow];

  if constexpr (CBF16) {
    ushort* Cb = (ushort*)Cout;
    ushort* ctu = smem;                       // 32 x 264 ushorts = 16.5 KB
#pragma unroll
    for (int h = 0; h < TM / 32; ++h) {
      __syncthreads();
#pragma unroll
      for (int m2 = 0; m2 < 2; ++m2) {
        const int mt = h * 2 + m2;
        const int lr0 = m2 * 16 + lgrp * 4;
#pragma unroll
        for (int nt = 0; nt < 4; ++nt) {
          const int col = wn + nt * 16 + lrow;
#pragma unroll
          for (int j = 0; j < 4; ++j)
            ctu[(lr0 + j) * 264 + col] = f2bf_rn(acc[mt][nt][j] + bb[nt]);
        }
      }
      __syncthreads();
#pragma unroll
      for (int i = 0; i < 4; ++i) {
        const int idx = i * 256 + tid, r = idx >> 5, c16 = (idx & 31) * 8;
        *(uint4*)&Cb[(size_t)(brow + h * 32 + r) * 256 + c16] =
            *(const uint4*)&ctu[r * 264 + c16];
      }
    }
  } else {
    float* C = (float*)Cout;
    float* ctile = (float*)smem;              // 16 x 260 floats (TM=32 path)
#pragma unroll
    for (int h = 0; h < MT; ++h) {
      __syncthreads();
#pragma unroll
      for (int nt = 0; nt < 4; ++nt) {
        const int col = wn + nt * 16 + lrow;
#pragma unroll
        for (int j = 0; j < 4; ++j)
          ctile[(lgrp * 4 + j) * 260 + col] = acc[h][nt][j] + bb[nt];
      }
      __syncthreads();
#pragma unroll
      for (int i = 0; i < 4; ++i) {   // 16 rows * 64 float4 / 256 threads
        const int idx = i * 256 + tid, r = idx >> 6, c4 = (idx & 63) << 2;
        *(float4*)&C[(size_t)(brow + h * 16 + r) * 256 + c4] =
            *(const float4*)&ctile[r * 260 + c4];
      }
    }
  }
}

// ---------------------------------------------------------------------------
// Weight prep, both weights fused: W fp32 [256][256] -> Bprep bf16 hi-only,
// pre-swizzled 32-k-chunk LDS images (64-B rows, pos = seg ^ fr(row)).
// Each Bprep = 8 chunks x 8192 ushorts = 128 KB.
// ---------------------------------------------------------------------------
__global__ __launch_bounds__(256) void prep_wt2(
    const float* __restrict__ Wv, const float* __restrict__ Wo,
    ushort* __restrict__ Bv, ushort* __restrict__ Bo)
{
  const int gid = blockIdx.x * 256 + threadIdx.x;  // 0..131071
  const float* W = (gid < 65536) ? Wv : Wo;
  ushort* Bp     = (gid < 65536) ? Bv : Bo;
  const int pg = gid & 65535;
  const int t = pg >> 13;
  const int p = pg & 8191;
  const int r = p >> 5;
  const int q = p & 31;
  const int gpos = q >> 3;
  const int j = q & 7;
  const int g0 = gpos ^ ((r >> 1) & 3);            // un-swizzled k-segment
  const int k = t * 32 + g0 * 8 + j;
  Bp[pg] = f2bf_rn(W[(size_t)k * 256 + r]);
}

// ---------------------------------------------------------------------------
// Offsets + attention-logits projection (unchanged).
// ---------------------------------------------------------------------------
__global__ __launch_bounds__(128) void proj_kernel(
    const float* __restrict__ query,
    const float* __restrict__ W_off, const float* __restrict__ b_off,
    const float* __restrict__ W_attn, const float* __restrict__ b_attn,
    float* __restrict__ offs, float* __restrict__ logits)
{
  __shared__ float q_lds[8][256];
  const int row0 = blockIdx.x * 8;
  const int tid  = threadIdx.x;

  for (int i = tid; i < 512; i += 128) {
    const int r  = i >> 6;
    const int c4 = (i & 63) << 2;
    *(float4*)&q_lds[r][c4] = *(const float4*)&query[(size_t)(row0 + r) * 256 + c4];
  }
  __syncthreads();
  if (tid >= 96) return;

  float acc[8] = {};
  if (tid < 64) {
    for (int k4 = 0; k4 < 256; k4 += 4) {
      const float w0 = W_off[(k4 + 0) * 64 + tid];
      const float w1 = W_off[(k4 + 1) * 64 + tid];
      const float w2 = W_off[(k4 + 2) * 64 + tid];
      const float w3 = W_off[(k4 + 3) * 64 + tid];
#pragma unroll
      for (int r = 0; r < 8; ++r) {
        float4 q4 = *(const float4*)&q_lds[r][k4];
        acc[r] += q4.x * w0 + q4.y * w1 + q4.z * w2 + q4.w * w3;
      }
    }
    const float bb = b_off[tid];
#pragma unroll
    for (int r = 0; r < 8; ++r)
      offs[(size_t)(row0 + r) * 64 + tid] = acc[r] + bb;
  } else {
    const int j = tid - 64;
    for (int k4 = 0; k4 < 256; k4 += 4) {
      const float w0 = W_attn[(k4 + 0) * 32 + j];
      const float w1 = W_attn[(k4 + 1) * 32 + j];
      const float w2 = W_attn[(k4 + 2) * 32 + j];
      const float w3 = W_attn[(k4 + 3) * 32 + j];
#pragma unroll
      for (int r = 0; r < 8; ++r) {
        float4 q4 = *(const float4*)&q_lds[r][k4];
        acc[r] += q4.x * w0 + q4.y * w1 + q4.z * w2 + q4.w * w3;
      }
    }
    const float bb = b_attn[j];
#pragma unroll
    for (int r = 0; r < 8; ++r)
      logits[(size_t)(row0 + r) * 32 + j] = acc[r] + bb;
  }
}

// ---------------------------------------------------------------------------
// Softmax + bilinear sampling, wave-per-query; bf16 values.
// r16: (1) batch-per-XCD block swizzle — XCD x processes only batch x, so
// each XCD's L2 holds one batch's values (5.1 MB) instead of thrashing all
// 8 (T1 mechanism; bijective since gridDim%8==0). (2) mid written as bf16
// (precision-neutral: gemm2 rounded A to bf16 anyway).
// ---------------------------------------------------------------------------
__global__ __launch_bounds__(256, 8) void sample_kernel(
    const float* __restrict__ refp,    // [BQ,2]
    const float* __restrict__ offs,    // [BQ,64]  (h*8 + p*2 + c)
    const float* __restrict__ logits,  // [BQ,32]  (h*4 + p)
    const ushort* __restrict__ values, // [B,HW,256] bf16
    ushort* __restrict__ mid,          // [BQ,256] bf16
    const int* __restrict__ hptr, const int* __restrict__ wptr,
    int Q, int HW)
{
  const int lane = threadIdx.x & 63;
  const int cpx  = (int)gridDim.x >> 3;            // blocks per XCD chunk
  const int blk  = (blockIdx.x & 7) * cpx + (blockIdx.x >> 3);
  const int bq   = blk * 4 + (threadIdx.x >> 6);
  const int b    = bq / Q;
  const int W_   = *wptr;
  const int H_   = *hptr;
  const int h    = lane >> 3;

  const float l0 = logits[(size_t)bq * 32 + h * 4 + 0];
  const float l1 = logits[(size_t)bq * 32 + h * 4 + 1];
  const float l2 = logits[(size_t)bq * 32 + h * 4 + 2];
  const float l3 = logits[(size_t)bq * 32 + h * 4 + 3];
  const float m  = fmaxf(fmaxf(l0, l1), fmaxf(l2, l3));
  const float e0 = __expf(l0 - m), e1 = __expf(l1 - m);
  const float e2 = __expf(l2 - m), e3 = __expf(l3 - m);
  const float inv = 1.0f / (e0 + e1 + e2 + e3);
  float wt[4] = {e0 * inv, e1 * inv, e2 * inv, e3 * inv};

  const float rx = refp[(size_t)bq * 2 + 0];
  const float ry = refp[(size_t)bq * 2 + 1];
  const ushort* vb = values + (size_t)b * HW * 256;
  const int ch = lane * 4;

  f32x4 acc = {0.f, 0.f, 0.f, 0.f};
#pragma unroll
  for (int p = 0; p < NPOINTS; ++p) {
    float lx = rx + offs[(size_t)bq * 64 + h * 8 + p * 2 + 0];
    float ly = ry + offs[(size_t)bq * 64 + h * 8 + p * 2 + 1];
    lx = fminf(fmaxf(lx, 0.0f), 1.0f);
    ly = fminf(fmaxf(ly, 0.0f), 1.0f);
    const float sx = lx * (float)(W_ - 1);
    const float sy = ly * (float)(H_ - 1);
    int x0 = (int)floorf(sx);
    int y0 = (int)floorf(sy);
    x0 = min(max(x0, 0), W_ - 1);
    y0 = min(max(y0, 0), H_ - 1);
    const int x1 = min(x0 + 1, W_ - 1);
    const int y1 = min(y0 + 1, H_ - 1);
    const float wx1 = sx - (float)x0, wx0 = 1.0f - wx1;
    const float wy1 = sy - (float)y0, wy0 = 1.0f - wy1;

    const ushort4 g00 = *(const ushort4*)&vb[(size_t)(y0 * W_ + x0) * 256 + ch];
    const ushort4 g10 = *(const ushort4*)&vb[(size_t)(y0 * W_ + x1) * 256 + ch];
    const ushort4 g01 = *(const ushort4*)&vb[(size_t)(y1 * W_ + x0) * 256 + ch];
    const ushort4 g11 = *(const ushort4*)&vb[(size_t)(y1 * W_ + x1) * 256 + ch];

    const float w00 = wx0 * wy0, w10 = wx1 * wy0, w01 = wx0 * wy1, w11 = wx1 * wy1;
    const float wp = wt[p];
    const float f00[4] = {bf2f(g00.x), bf2f(g00.y), bf2f(g00.z), bf2f(g00.w)};
    const float f10[4] = {bf2f(g10.x), bf2f(g10.y), bf2f(g10.z), bf2f(g10.w)};
    const float f01[4] = {bf2f(g01.x), bf2f(g01.y), bf2f(g01.z), bf2f(g01.w)};
    const float f11[4] = {bf2f(g11.x), bf2f(g11.y), bf2f(g11.z), bf2f(g11.w)};
#pragma unroll
    for (int j = 0; j < 4; ++j)
      acc[j] += wp * (f00[j] * w00 + f01[j] * w01 + f10[j] * w10 + f11[j] * w11);
  }
  ushort4 mo;
  mo.x = f2bf_rn(acc[0]); mo.y = f2bf_rn(acc[1]);
  mo.z = f2bf_rn(acc[2]); mo.w = f2bf_rn(acc[3]);
  *(ushort4*)&mid[(size_t)bq * 256 + ch] = mo;
}

// ---------------------------------------------------------------------------
extern "C" void kernel_launch(void* const* d_in, const int* in_sizes, int n_in,
                              void* d_out, int out_size, void* d_ws, size_t ws_size,
                              hipStream_t stream)
{
  const float* query   = (const float*)d_in[0];
  const float* refp    = (const float*)d_in[1];
  const float* input_f = (const float*)d_in[2];
  const int*   hptr    = (const int*)d_in[3];
  const int*   wptr    = (const int*)d_in[4];
  const float* W_off   = (const float*)d_in[5];
  const float* b_off   = (const float*)d_in[6];
  const float* W_attn  = (const float*)d_in[7];
  const float* b_attn  = (const float*)d_in[8];
  const float* W_val   = (const float*)d_in[9];
  const float* b_val   = (const float*)d_in[10];
  const float* W_out   = (const float*)d_in[11];
  const float* b_out   = (const float*)d_in[12];
  float* out = (float*)d_out;

  const int D   = 256;
  const int BQ  = in_sizes[0] / D;   // 16384
  const int B   = 8;
  const int Q   = BQ / B;            // 2048
  const int BHW = in_sizes[2] / D;   // 80000
  const int HW  = BHW / B;           // 10000

  char* ws = (char*)d_ws;
  ushort* values = (ushort*)ws;                                 // bf16: 40.96 MB
  size_t o = (size_t)BHW * D * sizeof(ushort);
  float* offsb  = (float*)(ws + o);  o += (size_t)BQ * 64 * sizeof(float);
  float* logitb = (float*)(ws + o);  o += (size_t)BQ * 32 * sizeof(float);
  ushort* midb  = (ushort*)(ws + o); o += (size_t)BQ * D * sizeof(ushort);  // bf16: 8.39 MB
  // Each Bprep = (D/32) chunks x 8192 ushorts = 128 KB (bf16 hi-only).
  ushort* Bprep_val = (ushort*)(ws + o);  o += (size_t)(D / 32) * 8192 * sizeof(ushort);
  ushort* Bprep_out = (ushort*)(ws + o);  o += (size_t)(D / 32) * 8192 * sizeof(ushort);

  // 0. both weight preps in one launch
  prep_wt2<<<512, 256, 0, stream>>>(W_val, W_out, Bprep_val, Bprep_out);

  // 1. values(bf16) = input_flatten @ W_val + b_val
  gemm_bf16_n256<64, true, false><<<BHW / 64, 256, 0, stream>>>(
      input_f, Bprep_val, b_val, (void*)values, BHW, D);

  // 2. offsets + attention logits
  proj_kernel<<<BQ / 8, 128, 0, stream>>>(
      query, W_off, b_off, W_attn, b_attn, offsb, logitb);

  // 3. softmax + bilinear sampling -> mid (bf16), batch-per-XCD swizzled
  sample_kernel<<<BQ / 4, 256, 0, stream>>>(
      refp, offsb, logitb, values, midb, hptr, wptr, Q, HW);

  // 4. out = mid @ W_out + b_out  (fp32 C, bf16 A via ABF16 path)
  gemm_bf16_n256<32, false, true><<<BQ / 32, 256, 0, stream>>>(
      (const void*)midb, Bprep_out, b_out, (void*)out, BQ, D);
}

// Round 18
// 66.645 us; speedup vs baseline: 2.0538x; 1.2645x over previous
//
#include <hip/hip_runtime.h>
#include <hip/hip_bf16.h>
#include <cstdint>

#define NHEADS 8
#define NPOINTS 4

typedef __bf16 bf16x8 __attribute__((ext_vector_type(8)));
typedef float f32x4 __attribute__((ext_vector_type(4)));

#define AS1 __attribute__((address_space(1)))
#define AS3 __attribute__((address_space(3)))

__device__ __forceinline__ ushort f2bf_rn(float x) {
  union { float f; uint32_t u; } c; c.f = x;
  uint32_t r = c.u + 0x7fffu + ((c.u >> 16) & 1u);
  return (ushort)(r >> 16);
}
__device__ __forceinline__ float bf2f(ushort h) {
  union { uint32_t u; float f; } c; c.u = ((uint32_t)h) << 16; return c.f;
}
__device__ __forceinline__ uint pack2(ushort a, ushort b) {
  return (uint)a | ((uint)b << 16);
}

// 64-B-row layout (r15, verified): 4 granules of 16 B, pos = seg ^ fr(row).
__device__ __forceinline__ int fr(int row) { return (row >> 1) & 3; }
__device__ __forceinline__ int aidx(int row, int gpos) { return row * 32 + gpos * 8; }

// 128-B-row split layout (r5-r13, verified): 8 granules, 0-3 hi / 4-7 lo,
// granule pos XOR-swizzled by (row&7).
__device__ __forceinline__ int gidx8(int row, int g0) {
  return row * 64 + ((g0 ^ (row & 7)) << 3);
}

// ---------------------------------------------------------------------------
// Pure-bf16 GEMM, N=256 (r15 structure, verified): B hi-only bf16, A+B
// double-buffered, B(t+1) glds a full step before the draining sync. BK=32.
// ABF16: A arrives bf16 (gemm2's mid) -> A-stage is a pure uint2 copy.
// LDS = 2*(TM*64B) + 2*16KB = 40 KB @ TM=64 -> 4 blocks/CU.
// ---------------------------------------------------------------------------
template<int TM, bool CBF16, bool ABF16>
__global__ __launch_bounds__(256, 4) void gemm_bf16_n256(
    const void* __restrict__ Ain,
    const ushort* __restrict__ Bprep,   // [K/32][8192] pre-swizzled ushorts
    const float* __restrict__ bias, void* __restrict__ Cout,
    int M, int K)
{
  constexpr int MT = TM / 16;
  constexpr int AH = TM * 32;
  constexpr int BH = 8192;
  __shared__ ushort smem[2 * AH + 2 * BH];
  const int tid  = threadIdx.x;
  const int lane = tid & 63, wave = tid >> 6;
  const int wn   = wave * 64;
  const int lrow = lane & 15, lgrp = lane >> 4;
  const long brow = (long)blockIdx.x * TM;
  const int NT = K >> 5;

  const float*  Af = (const float*)Ain;
  const ushort* A16 = (const ushort*)Ain;

  f32x4 acc[MT][4] = {};

  int arow, as_;
  if constexpr (TM == 64) { arow = tid >> 2; as_ = tid & 3; }
  else                    { arow = tid >> 3; as_ = tid & 7; }

  ushort* Acur = smem;
  ushort* Anxt = smem + AH;
  ushort* Bcur = smem + 2 * AH;
  ushort* Bnxt = smem + 2 * AH + BH;

  // ---- prologue ----
#pragma unroll
  for (int i = 0; i < 4; ++i)
    __builtin_amdgcn_global_load_lds(
        (const AS1 void*)(Bprep + wave * 2048 + (lane + 64 * i) * 8),
        (AS3 void*)(Bcur + wave * 2048 + (lane + 64 * i) * 8), 16, 0, 0);
  if constexpr (ABF16) {
    uint2 av = *(const uint2*)&A16[(size_t)(brow + arow) * K + as_ * 4];
    const int g = as_ >> 1, half = (as_ & 1) * 4;
    *(uint2*)&Acur[aidx(arow, g ^ fr(arow)) + half] = av;
  } else if constexpr (TM == 64) {
    const float* ap = &Af[(size_t)(brow + arow) * K] + as_ * 8;
    float4 a0 = *(const float4*)ap, a1 = *(const float4*)(ap + 4);
    const float v[8] = {a0.x, a0.y, a0.z, a0.w, a1.x, a1.y, a1.z, a1.w};
    ushort h[8];
#pragma unroll
    for (int j = 0; j < 8; ++j) h[j] = f2bf_rn(v[j]);
    uint4 hv = {pack2(h[0],h[1]), pack2(h[2],h[3]), pack2(h[4],h[5]), pack2(h[6],h[7])};
    *(uint4*)&Acur[aidx(arow, as_ ^ fr(arow))] = hv;
  } else {
    const int g = as_ >> 1, half = (as_ & 1) * 4;
    float4 a0 = *(const float4*)&Af[(size_t)(brow + arow) * K + g * 8 + half];
    ushort h[4] = {f2bf_rn(a0.x), f2bf_rn(a0.y), f2bf_rn(a0.z), f2bf_rn(a0.w)};
    uint2 hv = {pack2(h[0],h[1]), pack2(h[2],h[3])};
    *(uint2*)&Acur[aidx(arow, g ^ fr(arow)) + half] = hv;
  }
  __syncthreads();

  for (int t = 0; t < NT; ++t) {
    const bool more = (t + 1 < NT);

    if (more) {
#pragma unroll
      for (int i = 0; i < 4; ++i)
        __builtin_amdgcn_global_load_lds(
            (const AS1 void*)(Bprep + (size_t)(t + 1) * BH + wave * 2048 + (lane + 64 * i) * 8),
            (AS3 void*)(Bnxt + wave * 2048 + (lane + 64 * i) * 8), 16, 0, 0);
    }

    float4 a0 = {}, a1 = {};
    uint2 au = {};
    if (more) {
      if constexpr (ABF16) {
        au = *(const uint2*)&A16[(size_t)(brow + arow) * K + (t + 1) * 32 + as_ * 4];
      } else if constexpr (TM == 64) {
        const float* ap = &Af[(size_t)(brow + arow) * K] + (t + 1) * 32 + as_ * 8;
        a0 = *(const float4*)ap;
        a1 = *(const float4*)(ap + 4);
      } else {
        const int g = as_ >> 1, half = (as_ & 1) * 4;
        a0 = *(const float4*)&Af[(size_t)(brow + arow) * K + (t + 1) * 32 + g * 8 + half];
      }
    }

    bf16x8 ah[MT];
#pragma unroll
    for (int mt = 0; mt < MT; ++mt) {
      const int r = mt * 16 + lrow;
      ah[mt] = *(const bf16x8*)&Acur[aidx(r, lgrp ^ fr(r))];
    }
#pragma unroll
    for (int nt = 0; nt < 4; ++nt) {
      const int r = wn + nt * 16 + lrow;
      const bf16x8 b = *(const bf16x8*)&Bcur[aidx(r, lgrp ^ fr(r))];
#pragma unroll
      for (int mt = 0; mt < MT; ++mt)
        acc[mt][nt] = __builtin_amdgcn_mfma_f32_16x16x32_bf16(ah[mt], b, acc[mt][nt], 0, 0, 0);
    }

    if (more) {
      if constexpr (ABF16) {
        const int g = as_ >> 1, half = (as_ & 1) * 4;
        *(uint2*)&Anxt[aidx(arow, g ^ fr(arow)) + half] = au;
      } else if constexpr (TM == 64) {
        const float v[8] = {a0.x, a0.y, a0.z, a0.w, a1.x, a1.y, a1.z, a1.w};
        ushort h[8];
#pragma unroll
        for (int j = 0; j < 8; ++j) h[j] = f2bf_rn(v[j]);
        uint4 hv = {pack2(h[0],h[1]), pack2(h[2],h[3]), pack2(h[4],h[5]), pack2(h[6],h[7])};
        *(uint4*)&Anxt[aidx(arow, as_ ^ fr(arow))] = hv;
      } else {
        const int g = as_ >> 1, half = (as_ & 1) * 4;
        ushort h[4] = {f2bf_rn(a0.x), f2bf_rn(a0.y), f2bf_rn(a0.z), f2bf_rn(a0.w)};
        uint2 hv = {pack2(h[0],h[1]), pack2(h[2],h[3])};
        *(uint2*)&Anxt[aidx(arow, g ^ fr(arow)) + half] = hv;
      }
    }

    __syncthreads();
    ushort* tp;
    tp = Acur; Acur = Anxt; Anxt = tp;
    tp = Bcur; Bcur = Bnxt; Bnxt = tp;
  }

  // ---- epilogue ----
  float bb[4];
#pragma unroll
  for (int nt = 0; nt < 4; ++nt) bb[nt] = bias[wn + nt * 16 + lrow];

  if constexpr (CBF16) {
    ushort* Cb = (ushort*)Cout;
    ushort* ctu = smem;
#pragma unroll
    for (int h = 0; h < TM / 32; ++h) {
      __syncthreads();
#pragma unroll
      for (int m2 = 0; m2 < 2; ++m2) {
        const int mt = h * 2 + m2;
        const int lr0 = m2 * 16 + lgrp * 4;
#pragma unroll
        for (int nt = 0; nt < 4; ++nt) {
          const int col = wn + nt * 16 + lrow;
#pragma unroll
          for (int j = 0; j < 4; ++j)
            ctu[(lr0 + j) * 264 + col] = f2bf_rn(acc[mt][nt][j] + bb[nt]);
        }
      }
      __syncthreads();
#pragma unroll
      for (int i = 0; i < 4; ++i) {
        const int idx = i * 256 + tid, r = idx >> 5, c16 = (idx & 31) * 8;
        *(uint4*)&Cb[(size_t)(brow + h * 32 + r) * 256 + c16] =
            *(const uint4*)&ctu[r * 264 + c16];
      }
    }
  } else {
    float* C = (float*)Cout;
    float* ctile = (float*)smem;
#pragma unroll
    for (int h = 0; h < MT; ++h) {
      __syncthreads();
#pragma unroll
      for (int nt = 0; nt < 4; ++nt) {
        const int col = wn + nt * 16 + lrow;
#pragma unroll
        for (int j = 0; j < 4; ++j)
          ctile[(lgrp * 4 + j) * 260 + col] = acc[h][nt][j] + bb[nt];
      }
      __syncthreads();
#pragma unroll
      for (int i = 0; i < 4; ++i) {
        const int idx = i * 256 + tid, r = idx >> 6, c4 = (idx & 63) << 2;
        *(float4*)&C[(size_t)(brow + h * 16 + r) * 256 + c4] =
            *(const float4*)&ctile[r * 260 + c4];
      }
    }
  }
}

// ---------------------------------------------------------------------------
// proj as a split-3 MFMA mini-GEMM. pobuf[BQ,128] = query @ Wcat + bcat,
// Wcat = [W_off | W_attn | 0pad]. Split-3 required (offset errors amplify
// ~50x into the output). TM=32. 128-B-row layout (gidx8).
// r18 FIX: B chunk is 8192 ushorts -> staging is 4 iters (8 overflowed
// into Bnxt + raced between waves; r17's absmax 0.217).
// LDS: A 2x4KB + B 2x16KB = 40 KB.
// ---------------------------------------------------------------------------
__global__ __launch_bounds__(256, 2) void proj_gemm(
    const float* __restrict__ query,
    const ushort* __restrict__ Bprep,   // [8][8192] pre-swizzled (hi/lo)
    const float* __restrict__ b_off, const float* __restrict__ b_attn,
    float* __restrict__ pobuf)
{
  constexpr int AH = 32 * 64;    // 2048 ushorts per A buffer
  constexpr int BH = 8192;       // 128 rows x 64 ushorts per B buffer
  __shared__ ushort smem[2 * AH + 2 * BH];
  const int tid  = threadIdx.x;
  const int lane = tid & 63, wave = tid >> 6;
  const int wm   = (wave >> 1) * 16;
  const int wn   = (wave & 1) * 64;
  const int lrow = lane & 15, lgrp = lane >> 4;
  const long brow = (long)blockIdx.x * 32;

  f32x4 acc[4] = {};

  const int arow = tid >> 3, as_ = tid & 7;
  const float* Abase = &query[(size_t)(brow + arow) * 256];

  ushort* Acur = smem;
  ushort* Anxt = smem + AH;
  ushort* Bcur = smem + 2 * AH;
  ushort* Bnxt = smem + 2 * AH + BH;

  // ---- prologue: B(0) glds (4 iters = exactly BH) + A(0) split-stage ----
#pragma unroll
  for (int i = 0; i < 4; ++i)
    __builtin_amdgcn_global_load_lds(
        (const AS1 void*)(Bprep + wave * 2048 + (lane + 64 * i) * 8),
        (AS3 void*)(Bcur + wave * 2048 + (lane + 64 * i) * 8), 16, 0, 0);
  {
    const int g = as_ >> 1, half = (as_ & 1) * 4;
    float4 a0 = *(const float4*)(Abase + g * 8 + half);
    ushort h[4], l[4];
#pragma unroll
    for (int j = 0; j < 4; ++j) {
      const float v = ((const float*)&a0)[j];
      h[j] = f2bf_rn(v);
      l[j] = f2bf_rn(v - bf2f(h[j]));
    }
    *(uint2*)&Acur[gidx8(arow, g) + half]     = uint2{pack2(h[0],h[1]), pack2(h[2],h[3])};
    *(uint2*)&Acur[gidx8(arow, g + 4) + half] = uint2{pack2(l[0],l[1]), pack2(l[2],l[3])};
  }
  __syncthreads();

  for (int t = 0; t < 8; ++t) {
    const bool more = (t + 1 < 8);

    if (more) {
#pragma unroll
      for (int i = 0; i < 4; ++i)
        __builtin_amdgcn_global_load_lds(
            (const AS1 void*)(Bprep + (size_t)(t + 1) * BH + wave * 2048 + (lane + 64 * i) * 8),
            (AS3 void*)(Bnxt + wave * 2048 + (lane + 64 * i) * 8), 16, 0, 0);
    }

    float4 a0 = {};
    const int g = as_ >> 1, half = (as_ & 1) * 4;
    if (more)
      a0 = *(const float4*)(Abase + (t + 1) * 32 + g * 8 + half);

    // ---- MFMA(t): split-3, MT=1 ----
    const int ra = wm + lrow;
    const bf16x8 ah = *(const bf16x8*)&Acur[gidx8(ra, lgrp)];
    const bf16x8 al = *(const bf16x8*)&Acur[gidx8(ra, lgrp + 4)];
#pragma unroll
    for (int nt = 0; nt < 4; ++nt) {
      const int rb = wn + nt * 16 + lrow;
      const bf16x8 bh = *(const bf16x8*)&Bcur[gidx8(rb, lgrp)];
      const bf16x8 bl = *(const bf16x8*)&Bcur[gidx8(rb, lgrp + 4)];
      acc[nt] = __builtin_amdgcn_mfma_f32_16x16x32_bf16(ah, bh, acc[nt], 0, 0, 0);
      acc[nt] = __builtin_amdgcn_mfma_f32_16x16x32_bf16(ah, bl, acc[nt], 0, 0, 0);
      acc[nt] = __builtin_amdgcn_mfma_f32_16x16x32_bf16(al, bh, acc[nt], 0, 0, 0);
    }

    if (more) {
      ushort h[4], l[4];
#pragma unroll
      for (int j = 0; j < 4; ++j) {
        const float v = ((const float*)&a0)[j];
        h[j] = f2bf_rn(v);
        l[j] = f2bf_rn(v - bf2f(h[j]));
      }
      *(uint2*)&Anxt[gidx8(arow, g) + half]     = uint2{pack2(h[0],h[1]), pack2(h[2],h[3])};
      *(uint2*)&Anxt[gidx8(arow, g + 4) + half] = uint2{pack2(l[0],l[1]), pack2(l[2],l[3])};
    }

    __syncthreads();
    ushort* tp;
    tp = Acur; Acur = Anxt; Anxt = tp;
    tp = Bcur; Bcur = Bnxt; Bnxt = tp;
  }

  // ---- epilogue: LDS-staged full-row stores, bias inline ----
  __syncthreads();
  float* ctile = (float*)smem;                 // 32 x 132 floats = 16.9 KB
#pragma unroll
  for (int nt = 0; nt < 4; ++nt) {
    const int col = wn + nt * 16 + lrow;
    const float bb = (col < 64) ? b_off[col] : (col < 96 ? b_attn[col - 64] : 0.0f);
#pragma unroll
    for (int j = 0; j < 4; ++j)
      ctile[(wm + lgrp * 4 + j) * 132 + col] = acc[nt][j] + bb;
  }
  __syncthreads();
#pragma unroll
  for (int i = 0; i < 4; ++i) {                // 32 rows x 32 float4
    const int idx = i * 256 + tid, r = idx >> 5, c4 = (idx & 31) * 4;
    *(float4*)&pobuf[(size_t)(brow + r) * 128 + c4] = *(const float4*)&ctile[r * 132 + c4];
  }
}

// ---------------------------------------------------------------------------
// Weight prep (one launch): Wv/Wo -> 64-B-row bf16 hi-only tables (r15);
// Wcat = [W_off|W_attn|0] -> 128-B-row split hi/lo table for proj_gemm.
// ---------------------------------------------------------------------------
__global__ __launch_bounds__(256) void prep_wt3(
    const float* __restrict__ Wv, const float* __restrict__ Wo,
    const float* __restrict__ W_off, const float* __restrict__ W_attn,
    ushort* __restrict__ Bv, ushort* __restrict__ Bo, ushort* __restrict__ Bpo)
{
  const int gid = blockIdx.x * 256 + threadIdx.x;  // 0..196607
  if (gid < 131072) {
    const float* W = (gid < 65536) ? Wv : Wo;
    ushort* Bp     = (gid < 65536) ? Bv : Bo;
    const int pg = gid & 65535;
    const int t = pg >> 13;
    const int p = pg & 8191;
    const int r = p >> 5;
    const int q = p & 31;
    const int gpos = q >> 3;
    const int j = q & 7;
    const int g0 = gpos ^ ((r >> 1) & 3);
    const int k = t * 32 + g0 * 8 + j;
    Bp[pg] = f2bf_rn(W[(size_t)k * 256 + r]);
  } else {
    const int pg = gid - 131072;                   // 0..65535
    const int t = pg >> 13;
    const int p = pg & 8191;
    const int r = p >> 6;                          // col 0..127
    const int q = p & 63;
    const int gpos = q >> 3;
    const int j = q & 7;
    const int g0 = gpos ^ (r & 7);                 // 0-3 hi, 4-7 lo
    const int seg = g0 & 3, plane = g0 >> 2;
    const int k = t * 32 + seg * 8 + j;
    float w = 0.0f;
    if (r < 64)       w = W_off[(size_t)k * 64 + r];
    else if (r < 96)  w = W_attn[(size_t)k * 32 + (r - 64)];
    const ushort hi = f2bf_rn(w);
    Bpo[pg] = plane ? f2bf_rn(w - bf2f(hi)) : hi;
  }
}

// ---------------------------------------------------------------------------
// Softmax + bilinear sampling (r16 structure): batch-per-XCD swizzle,
// bf16 values, bf16 mid; offs/logits from fused pobuf[bq*128].
// ---------------------------------------------------------------------------
__global__ __launch_bounds__(256, 8) void sample_kernel(
    const float* __restrict__ refp,    // [BQ,2]
    const float* __restrict__ pobuf,   // [BQ,128]: 0-63 offs, 64-95 logits
    const ushort* __restrict__ values, // [B,HW,256] bf16
    ushort* __restrict__ mid,          // [BQ,256] bf16
    const int* __restrict__ hptr, const int* __restrict__ wptr,
    int Q, int HW)
{
  const int lane = threadIdx.x & 63;
  const int cpx  = (int)gridDim.x >> 3;
  const int blk  = (blockIdx.x & 7) * cpx + (blockIdx.x >> 3);
  const int bq   = blk * 4 + (threadIdx.x >> 6);
  const int b    = bq / Q;
  const int W_   = *wptr;
  const int H_   = *hptr;
  const int h    = lane >> 3;
  const float* po = pobuf + (size_t)bq * 128;

  const float l0 = po[64 + h * 4 + 0];
  const float l1 = po[64 + h * 4 + 1];
  const float l2 = po[64 + h * 4 + 2];
  const float l3 = po[64 + h * 4 + 3];
  const float m  = fmaxf(fmaxf(l0, l1), fmaxf(l2, l3));
  const float e0 = __expf(l0 - m), e1 = __expf(l1 - m);
  const float e2 = __expf(l2 - m), e3 = __expf(l3 - m);
  const float inv = 1.0f / (e0 + e1 + e2 + e3);
  float wt[4] = {e0 * inv, e1 * inv, e2 * inv, e3 * inv};

  const float rx = refp[(size_t)bq * 2 + 0];
  const float ry = refp[(size_t)bq * 2 + 1];
  const ushort* vb = values + (size_t)b * HW * 256;
  const int ch = lane * 4;

  f32x4 acc = {0.f, 0.f, 0.f, 0.f};
#pragma unroll
  for (int p = 0; p < NPOINTS; ++p) {
    float lx = rx + po[h * 8 + p * 2 + 0];
    float ly = ry + po[h * 8 + p * 2 + 1];
    lx = fminf(fmaxf(lx, 0.0f), 1.0f);
    ly = fminf(fmaxf(ly, 0.0f), 1.0f);
    const float sx = lx * (float)(W_ - 1);
    const float sy = ly * (float)(H_ - 1);
    int x0 = (int)floorf(sx);
    int y0 = (int)floorf(sy);
    x0 = min(max(x0, 0), W_ - 1);
    y0 = min(max(y0, 0), H_ - 1);
    const int x1 = min(x0 + 1, W_ - 1);
    const int y1 = min(y0 + 1, H_ - 1);
    const float wx1 = sx - (float)x0, wx0 = 1.0f - wx1;
    const float wy1 = sy - (float)y0, wy0 = 1.0f - wy1;

    const ushort4 g00 = *(const ushort4*)&vb[(size_t)(y0 * W_ + x0) * 256 + ch];
    const ushort4 g10 = *(const ushort4*)&vb[(size_t)(y0 * W_ + x1) * 256 + ch];
    const ushort4 g01 = *(const ushort4*)&vb[(size_t)(y1 * W_ + x0) * 256 + ch];
    const ushort4 g11 = *(const ushort4*)&vb[(size_t)(y1 * W_ + x1) * 256 + ch];

    const float w00 = wx0 * wy0, w10 = wx1 * wy0, w01 = wx0 * wy1, w11 = wx1 * wy1;
    const float wp = wt[p];
    const float f00[4] = {bf2f(g00.x), bf2f(g00.y), bf2f(g00.z), bf2f(g00.w)};
    const float f10[4] = {bf2f(g10.x), bf2f(g10.y), bf2f(g10.z), bf2f(g10.w)};
    const float f01[4] = {bf2f(g01.x), bf2f(g01.y), bf2f(g01.z), bf2f(g01.w)};
    const float f11[4] = {bf2f(g11.x), bf2f(g11.y), bf2f(g11.z), bf2f(g11.w)};
#pragma unroll
    for (int j = 0; j < 4; ++j)
      acc[j] += wp * (f00[j] * w00 + f01[j] * w01 + f10[j] * w10 + f11[j] * w11);
  }
  ushort4 mo;
  mo.x = f2bf_rn(acc[0]); mo.y = f2bf_rn(acc[1]);
  mo.z = f2bf_rn(acc[2]); mo.w = f2bf_rn(acc[3]);
  *(ushort4*)&mid[(size_t)bq * 256 + ch] = mo;
}

// ---------------------------------------------------------------------------
extern "C" void kernel_launch(void* const* d_in, const int* in_sizes, int n_in,
                              void* d_out, int out_size, void* d_ws, size_t ws_size,
                              hipStream_t stream)
{
  const float* query   = (const float*)d_in[0];
  const float* refp    = (const float*)d_in[1];
  const float* input_f = (const float*)d_in[2];
  const int*   hptr    = (const int*)d_in[3];
  const int*   wptr    = (const int*)d_in[4];
  const float* W_off   = (const float*)d_in[5];
  const float* b_off   = (const float*)d_in[6];
  const float* W_attn  = (const float*)d_in[7];
  const float* b_attn  = (const float*)d_in[8];
  const float* W_val   = (const float*)d_in[9];
  const float* b_val   = (const float*)d_in[10];
  const float* W_out   = (const float*)d_in[11];
  const float* b_out   = (const float*)d_in[12];
  float* out = (float*)d_out;

  const int D   = 256;
  const int BQ  = in_sizes[0] / D;   // 16384
  const int B   = 8;
  const int Q   = BQ / B;            // 2048
  const int BHW = in_sizes[2] / D;   // 80000
  const int HW  = BHW / B;           // 10000

  char* ws = (char*)d_ws;
  ushort* values = (ushort*)ws;                                 // bf16: 40.96 MB
  size_t o = (size_t)BHW * D * sizeof(ushort);
  float* pobuf  = (float*)(ws + o);  o += (size_t)BQ * 128 * sizeof(float);   // 8.39 MB
  ushort* midb  = (ushort*)(ws + o); o += (size_t)BQ * D * sizeof(ushort);    // 8.39 MB
  ushort* Bprep_val = (ushort*)(ws + o);  o += (size_t)8 * 8192 * sizeof(ushort);  // 128 KB
  ushort* Bprep_out = (ushort*)(ws + o);  o += (size_t)8 * 8192 * sizeof(ushort);  // 128 KB
  ushort* Bprep_po  = (ushort*)(ws + o);  o += (size_t)8 * 8192 * sizeof(ushort);  // 128 KB

  // 0. all weight preps in one launch
  prep_wt3<<<768, 256, 0, stream>>>(W_val, W_out, W_off, W_attn,
                                    Bprep_val, Bprep_out, Bprep_po);

  // 1. values(bf16) = input_flatten @ W_val + b_val
  gemm_bf16_n256<64, true, false><<<BHW / 64, 256, 0, stream>>>(
      input_f, Bprep_val, b_val, (void*)values, BHW, D);

  // 2. pobuf = query @ [W_off|W_attn|0] + bias  (split-3 MFMA)
  proj_gemm<<<BQ / 32, 256, 0, stream>>>(
      query, Bprep_po, b_off, b_attn, pobuf);

  // 3. softmax + bilinear sampling -> mid (bf16), batch-per-XCD swizzled
  sample_kernel<<<BQ / 4, 256, 0, stream>>>(
      refp, pobuf, values, midb, hptr, wptr, Q, HW);

  // 4. out = mid @ W_out + b_out  (fp32 C, bf16 A)
  gemm_bf16_n256<32, false, true><<<BQ / 32, 256, 0, stream>>>(
      (const void*)midb, Bprep_out, b_out, (void*)out, BQ, D);
}